// Round 13
// baseline (302.504 us; speedup 1.0000x reference)
//
#include <hip/hip_runtime.h>
#include <hip/hip_bf16.h>

// QDense: out = s * (U X U^H)[:128,:128] / tr + (1-s) * diag(softmax(rand_w))
// B=512, D=256, O=128.
// Round-13: two BARRIER-FREE streaming kernels (wave autonomy; no lockstep).
//   K1 (1024 blocks = (b,kh), 512 thr, NO LDS, no barriers):
//       Y[:, kh*64..] = X * U^T-ish (complex), X rows read wave-private in
//       fragment order, U as FRAGMENT-PACKED global (1KB/instr, L2-hot),
//       Y stored fragment-packed (512B/wave contiguous).
//   K2 (512 blocks = b, 512 thr): sub = U_sub * Y, trace from sub diagonal,
//       normalize/blend.  A = unpacked U rows (infrequent), B = packed-Y
//       coalesced reads.  r2-proven structure.
// Failure modes fixed vs r2/r6: packed U (no 16-line scatter), packed-Y
// coalesced stores (no RMW amplification), launch_bounds(512,2) only (the
// (N,4) variants clamp VGPR to 64 and spill - r6/r10/r11 evidence).
//
// Y fragment layout frag(b,kg,jg), lane l: j = jg*16+(l>>4)*4..+4,
// k' = kg*16+(l&15); addr = (((b*8+kg)*16+jg)*64+l)*4 shorts.
// Packed-U frag(g,s), lane l: row = g*16+(l&15), k = s*32+(l>>4)*8..+8;
// addr = ((g*8+s)*64+l)*8 shorts.

typedef __attribute__((ext_vector_type(4))) float f32x4;
typedef __attribute__((ext_vector_type(8))) short bf16x8;

static __device__ __forceinline__ short f2bf(float f) {   // prep kernels only
    unsigned u = __float_as_uint(f);
    u += 0x7fffu + ((u >> 16) & 1u);
    return (short)(u >> 16);
}

static __device__ __forceinline__ unsigned cvtpk2(float lo, float hi) {
    union { __hip_bfloat162 h; unsigned u; } c;
    c.h = __float22bfloat162_rn(float2{lo, hi});
    return c.u;
}

static __device__ __forceinline__ bf16x8 pack8(f32x4 a, f32x4 b) {
    union { unsigned u[4]; bf16x8 v; } r;
    r.u[0] = cvtpk2(a[0], a[1]);
    r.u[1] = cvtpk2(a[2], a[3]);
    r.u[2] = cvtpk2(b[0], b[1]);
    r.u[3] = cvtpk2(b[2], b[3]);
    return r.v;
}

static __device__ __forceinline__ f32x4 mfma16(bf16x8 a, bf16x8 b, f32x4 c) {
    return __builtin_amdgcn_mfma_f32_16x16x32_bf16(a, b, c, 0, 0, 0);
}

// ---- prep: U rows [0,128) -> bf16, both unpacked (K2-A) and packed (K1-B) ----
__global__ void qprep_u(const float* __restrict__ wt,
                        short* __restrict__ Ur,  short* __restrict__ Ui,
                        short* __restrict__ Upr, short* __restrict__ Upi) {
    int idx = blockIdx.x * 256 + threadIdx.x;     // j*256+k, j<128
    int j = idx >> 8, k = idx & 255;
    float2 v = ((const float2*)wt)[idx];
    short br = f2bf(v.x), bi = f2bf(v.y);
    Ur[idx] = br;
    Ui[idx] = bi;
    int g = j >> 4, s = k >> 5;
    int lanep = (j & 15) | (((k >> 3) & 3) << 4);
    int p = ((g * 8 + s) * 64 + lanep) * 8 + (k & 7);
    Upr[p] = br;
    Upi[p] = bi;
}

// ---- prep: p = softmax(rand_w), s = sigmoid(lam) ----
__global__ void qprep_ps(const float* __restrict__ rw, const float* __restrict__ lm,
                         float* __restrict__ pv, float* __restrict__ sv) {
    int t = threadIdx.x;                           // 64 threads
    float w0 = rw[t], w1 = rw[t + 64];
    float m = fmaxf(w0, w1);
    #pragma unroll
    for (int o = 32; o > 0; o >>= 1) m = fmaxf(m, __shfl_xor(m, o));
    float e0 = expf(w0 - m), e1 = expf(w1 - m);
    float ss = e0 + e1;
    #pragma unroll
    for (int o = 32; o > 0; o >>= 1) ss += __shfl_xor(ss, o);
    pv[t] = e0 / ss;
    pv[t + 64] = e1 / ss;
    if (t == 0) sv[0] = 1.f / (1.f + expf(-lm[0]));
}

// ---- K1: Y frags = X * U_half^H.  No LDS, no barriers, free-running. ----
__global__ __launch_bounds__(512, 2) void qk1(
    const float* __restrict__ xr, const float* __restrict__ xi,
    const short* __restrict__ Upr, const short* __restrict__ Upi,
    short* __restrict__ Ypr, short* __restrict__ Ypi)
{
    const int bx   = blockIdx.x;
    const int b    = bx >> 1;
    const int kh   = bx & 1;
    const int tid  = threadIdx.x;
    const int lane = tid & 63;
    const int w    = tid >> 6;           // 0..7
    const int c16  = lane & 15;
    const int g4   = lane >> 4;

    const int ja  = (w & 3) * 16;        // j-group within each jt pass
    const int kg0 = kh * 4 + (w >> 2) * 2;     // U/Y frag-group base (+nt)
    const int l8  = lane * 8;

    f32x4 zero = {0.f, 0.f, 0.f, 0.f};

    for (int jt = 0; jt < 256; jt += 64) {       // 4 independent passes
        f32x4 yR0 = zero, yR1 = zero, yI0 = zero, yI1 = zero;

        const float* xrr = xr + ((size_t)b << 16) + (size_t)(jt + ja + c16) * 256 + g4 * 8;
        const float* xir = xi + ((size_t)b << 16) + (size_t)(jt + ja + c16) * 256 + g4 * 8;

        #pragma unroll
        for (int ks = 0; ks < 8; ++ks) {
            f32x4 a0 = *(const f32x4*)(xrr + ks * 32);
            f32x4 a1 = *(const f32x4*)(xrr + ks * 32 + 4);
            f32x4 b0 = *(const f32x4*)(xir + ks * 32);
            f32x4 b1 = *(const f32x4*)(xir + ks * 32 + 4);
            bf16x8 axr  = pack8(a0, a1);
            bf16x8 axi  = pack8(b0, b1);
            bf16x8 axrn = axr ^ (short)0x8000;

            // nt = 0
            {
                const int fo = ((kg0 * 8 + ks) << 9) + l8;
                bf16x8 bur = *(const bf16x8*)(Upr + fo);
                bf16x8 bui = *(const bf16x8*)(Upi + fo);
                yR0 = mfma16(axr,  bur, yR0);
                yR0 = mfma16(axi,  bui, yR0);
                yI0 = mfma16(axi,  bur, yI0);
                yI0 = mfma16(axrn, bui, yI0);
            }
            // nt = 1
            {
                const int fo = (((kg0 + 1) * 8 + ks) << 9) + l8;
                bf16x8 bur = *(const bf16x8*)(Upr + fo);
                bf16x8 bui = *(const bf16x8*)(Upi + fo);
                yR1 = mfma16(axr,  bur, yR1);
                yR1 = mfma16(axi,  bui, yR1);
                yI1 = mfma16(axi,  bur, yI1);
                yI1 = mfma16(axrn, bui, yI1);
            }
        }

        // store fragment-packed Y: 8 B/lane, 512 B/wave contiguous
        const int jg = (jt >> 4) + (w & 3);
        {
            size_t po = ((((size_t)b * 8 + kg0) * 16 + jg) * 64 + lane) * 4;
            uint2 v;
            v.x = cvtpk2(yR0[0], yR0[1]); v.y = cvtpk2(yR0[2], yR0[3]);
            *(uint2*)(Ypr + po) = v;
            v.x = cvtpk2(yI0[0], yI0[1]); v.y = cvtpk2(yI0[2], yI0[3]);
            *(uint2*)(Ypi + po) = v;
        }
        {
            size_t po = ((((size_t)b * 8 + kg0 + 1) * 16 + jg) * 64 + lane) * 4;
            uint2 v;
            v.x = cvtpk2(yR1[0], yR1[1]); v.y = cvtpk2(yR1[2], yR1[3]);
            *(uint2*)(Ypr + po) = v;
            v.x = cvtpk2(yI1[0], yI1[1]); v.y = cvtpk2(yI1[2], yI1[3]);
            *(uint2*)(Ypi + po) = v;
        }
    }
}

// ---- K2: sub = U_sub * Y + trace/normalize/blend.  r2-proven. ----
__global__ __launch_bounds__(512, 2) void qk2(
    const short* __restrict__ Urg, const short* __restrict__ Uig,
    const short* __restrict__ Ypr, const short* __restrict__ Ypi,
    const float* __restrict__ pv, const float* __restrict__ sv,
    float* __restrict__ out)
{
    __shared__ float red[8];
    const int b    = blockIdx.x;
    const int tid  = threadIdx.x;
    const int lane = tid & 63;
    const int w    = tid >> 6;
    const int c16  = lane & 15;
    const int g4   = lane >> 4;
    const int wm   = w >> 2;             // i-half
    const int wn   = w & 3;              // k'-quarter

    f32x4 zero = {0.f, 0.f, 0.f, 0.f};
    f32x4 sR[4][2], sI[4][2];
    #pragma unroll
    for (int m = 0; m < 4; ++m)
        #pragma unroll
        for (int n = 0; n < 2; ++n) { sR[m][n] = zero; sI[m][n] = zero; }

    #pragma unroll 2
    for (int ks = 0; ks < 8; ++ks) {       // contraction over j, 32 per step
        bf16x8 aur[4], aui[4], auin[4];
        #pragma unroll
        for (int mt = 0; mt < 4; ++mt) {
            int i = wm * 64 + mt * 16 + c16;
            aur[mt]  = *(const bf16x8*)(Urg + (size_t)i * 256 + ks * 32 + g4 * 8);
            aui[mt]  = *(const bf16x8*)(Uig + (size_t)i * 256 + ks * 32 + g4 * 8);
            auin[mt] = aui[mt] ^ (short)0x8000;
        }
        #pragma unroll
        for (int nt = 0; nt < 2; ++nt) {
            int kg = wn * 2 + nt;
            int jg = ks * 2 + (g4 >> 1);
            size_t base = (((size_t)b * 8 + kg) * 16 + jg) * 64;
            int l0 = (g4 & 1) * 32 + c16;
            union { uint2 u2[2]; bf16x8 v; } br, bi;
            br.u2[0] = *(const uint2*)(Ypr + (base + l0) * 4);
            br.u2[1] = *(const uint2*)(Ypr + (base + l0 + 16) * 4);
            bi.u2[0] = *(const uint2*)(Ypi + (base + l0) * 4);
            bi.u2[1] = *(const uint2*)(Ypi + (base + l0 + 16) * 4);
            #pragma unroll
            for (int mt = 0; mt < 4; ++mt) {
                // sub_r = Ur Yr - Ui Yi ; sub_i = Ui Yr + Ur Yi
                sR[mt][nt] = mfma16(aur[mt],  br.v, sR[mt][nt]);
                sR[mt][nt] = mfma16(auin[mt], bi.v, sR[mt][nt]);
                sI[mt][nt] = mfma16(aui[mt],  br.v, sI[mt][nt]);
                sI[mt][nt] = mfma16(aur[mt],  bi.v, sI[mt][nt]);
            }
        }
    }

    // ---------- trace from sub diagonal ----------
    float loc = 0.f;
    #pragma unroll
    for (int mt = 0; mt < 4; ++mt)
        #pragma unroll
        for (int nt = 0; nt < 2; ++nt) {
            int colc = wn * 32 + nt * 16 + c16;
            #pragma unroll
            for (int r = 0; r < 4; ++r) {
                int row = wm * 64 + mt * 16 + g4 * 4 + r;
                if (row == colc) loc += sR[mt][nt][r];
            }
        }
    #pragma unroll
    for (int o = 32; o > 0; o >>= 1) loc += __shfl_xor(loc, o);
    if (lane == 0) red[w] = loc;
    __syncthreads();
    float tr = red[0] + red[1] + red[2] + red[3] + red[4] + red[5] + red[6] + red[7];

    // ---------- epilogue ----------
    float s     = sv[0];
    float inv   = s / tr;
    float onems = 1.f - s;
    float* outr = out + (size_t)b * 16384;
    float* outi = out + 8388608 + (size_t)b * 16384;

    #pragma unroll
    for (int mt = 0; mt < 4; ++mt)
        #pragma unroll
        for (int nt = 0; nt < 2; ++nt) {
            int colc = wn * 32 + nt * 16 + c16;
            #pragma unroll
            for (int r = 0; r < 4; ++r) {
                int row = wm * 64 + mt * 16 + g4 * 4 + r;
                float vr = sR[mt][nt][r] * inv;
                if (row == colc) vr += onems * pv[row];
                outr[row * 128 + colc] = vr;
                outi[row * 128 + colc] = sI[mt][nt][r] * inv;
            }
        }
}

extern "C" void kernel_launch(void* const* d_in, const int* in_sizes, int n_in,
                              void* d_out, int out_size, void* d_ws, size_t ws_size,
                              hipStream_t stream) {
    (void)in_sizes; (void)n_in; (void)out_size; (void)ws_size;
    const float* xr = (const float*)d_in[0];
    const float* xi = (const float*)d_in[1];
    const float* wt = (const float*)d_in[2];
    const float* rw = (const float*)d_in[3];
    const float* lm = (const float*)d_in[4];

    short* Ur  = (short*)d_ws;                        // 64 KB unpacked
    short* Ui  = (short*)((char*)d_ws + 65536);       // 64 KB
    short* Upr = (short*)((char*)d_ws + 131072);      // 64 KB packed frags
    short* Upi = (short*)((char*)d_ws + 196608);      // 64 KB
    float* pv  = (float*)((char*)d_ws + 262144);      // 128 f32
    float* sv  = pv + 128;                            // 1 f32
    short* Ypr = (short*)((char*)d_ws + 266240);      // 33.55 MB frag-packed Y
    short* Ypi = (short*)((char*)d_ws + 266240 + 33554432);
    float* o   = (float*)d_out;

    qprep_u<<<dim3(128), dim3(256), 0, stream>>>(wt, Ur, Ui, Upr, Upi);
    qprep_ps<<<dim3(1), dim3(64), 0, stream>>>(rw, lm, pv, sv);
    qk1<<<dim3(1024), dim3(512), 0, stream>>>(xr, xi, Upr, Upi, Ypr, Ypi);
    qk2<<<dim3(512), dim3(512), 0, stream>>>(Ur, Ui, Ypr, Ypi, pv, sv, o);
}

// Round 14
// 171.229 us; speedup vs baseline: 1.7667x; 1.7667x over previous
//
#include <hip/hip_runtime.h>
#include <hip/hip_bf16.h>

// QDense: out = s * (U X U^H)[:128,:128] / tr + (1-s) * diag(softmax(rand_w))
// B=512, D=256, O=128.
// Round-14: fused, TA-friendly.  All X global loads are FULL-ROW 1KB
// contiguous wave-loads (lane l -> base + l*16B), converted f32->bf16 at
// staging into a 4-slot LDS ring (slot = 16 j-rows x 256 k x {R,I} bf16,
// 16 KB).  Phase-pair q: consume slot-pair (q&1) [8 waves = 2 slices x
// 4 k'-groups], stage pair (q+1)&1 (issue-early / ds_write-late, T14).
// 1 barrier per pair, lgkmcnt(0) only - vmcnt stays counted.
// Stage-B A-operand = fragment-PACKED U (1KB coalesced).  Trace ks rotated
// per-wave so its 2 trace slices are steps 0,1 (no divergent branches).
// LDS: U 64K + Yt 16K + X-ring 64K = 144KB -> 1 block/CU.
// 1024 blocks (b = bx>>1, k'-half kh = bx&1), 512 thr.

typedef __attribute__((ext_vector_type(4))) float f32x4;
typedef __attribute__((ext_vector_type(8))) short bf16x8;

static __device__ __forceinline__ short f2bf(float f) {   // prep kernels only
    unsigned u = __float_as_uint(f);
    u += 0x7fffu + ((u >> 16) & 1u);
    return (short)(u >> 16);
}

static __device__ __forceinline__ unsigned cvtpk2(float lo, float hi) {
    union { __hip_bfloat162 h; unsigned u; } c;
    c.h = __float22bfloat162_rn(float2{lo, hi});
    return c.u;
}

static __device__ __forceinline__ uint2 cvt2(f32x4 v) {
    uint2 r;
    r.x = cvtpk2(v[0], v[1]);
    r.y = cvtpk2(v[2], v[3]);
    return r;
}

static __device__ __forceinline__ f32x4 mfma16(bf16x8 a, bf16x8 b, f32x4 c) {
    return __builtin_amdgcn_mfma_f32_16x16x32_bf16(a, b, c, 0, 0, 0);
}

// ---- prep: U -> bf16 row-major (Ur/Ui) and fragment-packed (Upr/Upi) ----
__global__ void qprep_u(const float* __restrict__ wt,
                        short* __restrict__ Ur,  short* __restrict__ Ui,
                        short* __restrict__ Upr, short* __restrict__ Upi) {
    int idx = blockIdx.x * 256 + threadIdx.x;     // j*256+k, j<128
    int j = idx >> 8, k = idx & 255;
    float2 v = ((const float2*)wt)[idx];
    short br = f2bf(v.x), bi = f2bf(v.y);
    Ur[idx] = br;
    Ui[idx] = bi;
    int g = j >> 4, s = k >> 5;
    int lanep = (j & 15) | (((k >> 3) & 3) << 4);
    int p = ((g * 8 + s) * 64 + lanep) * 8 + (k & 7);
    Upr[p] = br;
    Upi[p] = bi;
}

__global__ void qprep_ps(const float* __restrict__ rw, const float* __restrict__ lm,
                         float* __restrict__ pv, float* __restrict__ sv) {
    int t = threadIdx.x;
    float w0 = rw[t], w1 = rw[t + 64];
    float m = fmaxf(w0, w1);
    #pragma unroll
    for (int o = 32; o > 0; o >>= 1) m = fmaxf(m, __shfl_xor(m, o));
    float e0 = expf(w0 - m), e1 = expf(w1 - m);
    float ss = e0 + e1;
    #pragma unroll
    for (int o = 32; o > 0; o >>= 1) ss += __shfl_xor(ss, o);
    pv[t] = e0 / ss;
    pv[t + 64] = e1 / ss;
    if (t == 0) sv[0] = 1.f / (1.f + expf(-lm[0]));
}

__global__ void qprep_q(const float* __restrict__ wt,
                        short* __restrict__ Qrb, short* __restrict__ Qib) {
    int j = blockIdx.x;
    int k = threadIdx.x;
    float ar = 0.f, ai = 0.f;
    for (int i = 0; i < 128; ++i) {
        float2 uk = ((const float2*)wt)[i * 256 + k];
        float2 uj = ((const float2*)wt)[i * 256 + j];
        ar += uk.x * uj.x + uk.y * uj.y;
        ai += uk.x * uj.y - uk.y * uj.x;
    }
    Qrb[j * 256 + k] = f2bf(ar);
    Qib[j * 256 + k] = f2bf(ai);
}

// pair q: this-pair row base / next-pair row base (rows within batch, 0..255)
#define SBASE(Q) (((Q) >> 1) * 64 + ((Q) & 1) * 32)
#define NBASE(Q) ((((Q) + 1) >> 1) * 64 + (((Q) + 1) & 1) * 32)

// ---- consume one rotated ks step (KS, TR: 0 none / 1 q0 / 2 q1) ----
#define CONS(KS, TR) do {                                                       \
    const int ke = ((KS) + kk0) & 7;                                            \
    const int ko = ke * 64 + g16;                                               \
    bf16x8 axr = *(const bf16x8*)(xsp + aro + (ko ^ aswz));                     \
    bf16x8 axi = *(const bf16x8*)(xsp + 8192 + aro + (ko ^ aswz));              \
    bf16x8 bur = *(const bf16x8*)(smem + uob + (ko ^ uswz));                    \
    bf16x8 bui = *(const bf16x8*)(smem + 32768 + uob + (ko ^ uswz));            \
    bf16x8 axrn = axr ^ (short)0x8000;                                          \
    yR = mfma16(axr,  bur, yR);                                                 \
    yR = mfma16(axi,  bui, yR);                                                 \
    yI = mfma16(axi,  bur, yI);                                                 \
    yI = mfma16(axrn, bui, yI);                                                 \
    if ((TR) == 1) {                                                            \
        bf16x8 axin = axi ^ (short)0x8000;                                      \
        tr4 = mfma16(axr,  q0r, tr4);                                           \
        tr4 = mfma16(axin, q0i, tr4);                                           \
    }                                                                           \
    if ((TR) == 2) {                                                            \
        bf16x8 axin = axi ^ (short)0x8000;                                      \
        tr4 = mfma16(axr,  q1r, tr4);                                           \
        tr4 = mfma16(axin, q1i, tr4);                                           \
    }                                                                           \
} while (0)

// ---- one phase-pair (Q literal 0..7; LAST=1 for Q==7) ----
#define PAIR(Q, LAST) do {                                                      \
    const char* xsp = smem + 81920 + ((Q) & 1) * 32768 + wj16k;                 \
    /* issue slice-0 stage loads of next pair (full-row 1KB coalesced) */       \
    f32x4 sa0, sa1, sa2, sa3;                                                   \
    if (!(LAST)) {                                                              \
        const int gr0 = (NBASE(Q) + sr0) * 256 + xl4;                           \
        const int gr1 = (NBASE(Q) + sr1) * 256 + xl4;                           \
        sa0 = *(const f32x4*)(xr + xgb + gr0);                                  \
        sa1 = *(const f32x4*)(xr + xgb + gr1);                                  \
        sa2 = *(const f32x4*)(xi + xgb + gr0);                                  \
        sa3 = *(const f32x4*)(xi + xgb + gr1);                                  \
    }                                                                           \
    __builtin_amdgcn_sched_barrier(0);                                          \
    CONS(0, 1);                                                                 \
    CONS(1, 2);                                                                 \
    CONS(2, 0);                                                                 \
    CONS(3, 0);                                                                 \
    /* ds_write slice-0; prefetch next-pair Q; issue slice-1 loads */           \
    f32x4 sb0, sb1, sb2, sb3;                                                   \
    if (!(LAST)) {                                                              \
        char* wp = smem + 81920 + (((Q) + 1) & 1) * 32768;                      \
        *(uint2*)(wp + wr0o)        = cvt2(sa0);                                \
        *(uint2*)(wp + wr1o)        = cvt2(sa1);                                \
        *(uint2*)(wp + 8192 + wr0o) = cvt2(sa2);                                \
        *(uint2*)(wp + 8192 + wr1o) = cvt2(sa3);                                \
        const int qb = (NBASE(Q) + wj * 16 + c16) * 256 + kk0 * 32 + g8;        \
        q0r = *(const bf16x8*)(Qrb + qb);                                       \
        q0i = *(const bf16x8*)(Qib + qb);                                       \
        q1r = *(const bf16x8*)(Qrb + qb + 32);                                  \
        q1i = *(const bf16x8*)(Qib + qb + 32);                                  \
        const int gr0 = (NBASE(Q) + 16 + sr0) * 256 + xl4;                      \
        const int gr1 = (NBASE(Q) + 16 + sr1) * 256 + xl4;                      \
        sb0 = *(const f32x4*)(xr + xgb + gr0);                                  \
        sb1 = *(const f32x4*)(xr + xgb + gr1);                                  \
        sb2 = *(const f32x4*)(xi + xgb + gr0);                                  \
        sb3 = *(const f32x4*)(xi + xgb + gr1);                                  \
    }                                                                           \
    __builtin_amdgcn_sched_barrier(0);                                          \
    CONS(4, 0);                                                                 \
    CONS(5, 0);                                                                 \
    CONS(6, 0);                                                                 \
    CONS(7, 0);                                                                 \
    if (!(LAST)) {                                                              \
        char* wp = smem + 81920 + (((Q) + 1) & 1) * 32768 + 16384;              \
        *(uint2*)(wp + wr0o)        = cvt2(sb0);                                \
        *(uint2*)(wp + wr1o)        = cvt2(sb1);                                \
        *(uint2*)(wp + 8192 + wr0o) = cvt2(sb2);                                \
        *(uint2*)(wp + 8192 + wr1o) = cvt2(sb3);                                \
    }                                                                           \
    /* Yt write for my (j16, k'16) tile of this pair */                         \
    {                                                                           \
        const int yw = ((Q) & 1) ? ytw1 : ytw0;                                 \
        *(uint2*)(smem + 65536 + yw) = cvt2(yR);                                \
        *(uint2*)(smem + 73728 + yw) = cvt2(yI);                                \
    }                                                                           \
    yR = zero; yI = zero;                                                       \
    asm volatile("s_waitcnt lgkmcnt(0)" ::: "memory");                          \
    __builtin_amdgcn_sched_barrier(0);                                          \
    __builtin_amdgcn_s_barrier();                                               \
    __builtin_amdgcn_sched_barrier(0);                                          \
} while (0)

// ---- stage B (packed-U A-operand; Yt reads r9-proven) ----
#define STAGEB_KS(JT, KS2) do {                                                 \
    const int s2 = (JT) * 2 + (KS2);                                            \
    bf16x8 aur0 = *(const bf16x8*)(Upr + ((wm * 2 + 0) * 8 + s2) * 512 + l8);   \
    bf16x8 aui0 = *(const bf16x8*)(Upi + ((wm * 2 + 0) * 8 + s2) * 512 + l8);   \
    bf16x8 aur1 = *(const bf16x8*)(Upr + ((wm * 2 + 1) * 8 + s2) * 512 + l8);   \
    bf16x8 aui1 = *(const bf16x8*)(Upi + ((wm * 2 + 1) * 8 + s2) * 512 + l8);   \
    bf16x8 auin0 = aui0 ^ (short)0x8000;                                        \
    bf16x8 auin1 = aui1 ^ (short)0x8000;                                        \
    {                                                                           \
        const int off = ybA + (((KS2) * 64 + g16) ^ ysA);                       \
        bf16x8 byr = *(const bf16x8*)(smem + 65536 + off);                      \
        bf16x8 byi = *(const bf16x8*)(smem + 73728 + off);                      \
        sR00 = mfma16(aur0,  byr, sR00); sR00 = mfma16(auin0, byi, sR00);       \
        sI00 = mfma16(aui0,  byr, sI00); sI00 = mfma16(aur0,  byi, sI00);       \
        sR10 = mfma16(aur1,  byr, sR10); sR10 = mfma16(auin1, byi, sR10);       \
        sI10 = mfma16(aui1,  byr, sI10); sI10 = mfma16(aur1,  byi, sI10);       \
    }                                                                           \
    {                                                                           \
        const int off = ybB + (((KS2) * 64 + g16) ^ ysB);                       \
        bf16x8 byr = *(const bf16x8*)(smem + 65536 + off);                      \
        bf16x8 byi = *(const bf16x8*)(smem + 73728 + off);                      \
        sR01 = mfma16(aur0,  byr, sR01); sR01 = mfma16(auin0, byi, sR01);       \
        sI01 = mfma16(aui0,  byr, sI01); sI01 = mfma16(aur0,  byi, sI01);       \
        sR11 = mfma16(aur1,  byr, sR11); sR11 = mfma16(auin1, byi, sR11);       \
        sI11 = mfma16(aui1,  byr, sI11); sI11 = mfma16(aur1,  byi, sI11);       \
    }                                                                           \
} while (0)

#define STAGEB_PASS(JT) do {                                                    \
    STAGEB_KS(JT, 0);                                                           \
    STAGEB_KS(JT, 1);                                                           \
    asm volatile("s_waitcnt lgkmcnt(0)" ::: "memory");                          \
    __builtin_amdgcn_sched_barrier(0);                                          \
    __builtin_amdgcn_s_barrier();      /* Yt reads done before next writes */   \
    __builtin_amdgcn_sched_barrier(0);                                          \
} while (0)

// ---- main fused kernel ----
__global__ __launch_bounds__(512, 1) void qfused(
    const float* __restrict__ xr, const float* __restrict__ xi,
    const short* __restrict__ Urg, const short* __restrict__ Uig,
    const short* __restrict__ Upr, const short* __restrict__ Upi,
    const short* __restrict__ Qrb, const short* __restrict__ Qib,
    const float* __restrict__ pv, const float* __restrict__ sv,
    float* __restrict__ out)
{
    // [0,65536) U-half swizzled (R 0, I 32768); [65536,81920) Yt (R/I);
    // [81920,147456) X ring: 4 slots x (R[16x512B] + I at +8192).
    __shared__ __align__(16) char smem[147456];

    const int bx   = blockIdx.x;
    const int b    = bx >> 1;
    const int kh   = bx & 1;
    const int tid  = threadIdx.x;
    const int lane = tid & 63;
    const int w    = tid >> 6;
    const int c16  = lane & 15;
    const int g4   = lane >> 4;
    const int g8   = g4 * 8;
    const int g16  = g4 * 16;
    const int l8   = lane * 8;

    const int wj    = w >> 2;            // my slice within pair (0/1)
    const int wk    = w & 3;             // my k'-group
    const int kk0   = wk * 2;            // my trace-ks base (rotation)
    const int wj16k = wj * 16384;
    const int wm    = w >> 1;            // stage-B row-quarter (r9)
    const int wn    = w & 1;             // stage-B k'-half-of-half (r9)

    // X staging: wave stages slot-rows {w*2, w*2+1}; lane covers bytes l*16.
    const int sr0 = w * 2, sr1 = w * 2 + 1;
    const int xl4 = lane * 4;            // float offset within row
    const int xgb = b << 16;
    const int wr0o = sr0 * 512 + ((((lane >> 1) << 4) ^ ((sr0 & 7) << 4))) + ((lane & 1) << 3);
    const int wr1o = sr1 * 512 + ((((lane >> 1) << 4) ^ ((sr1 & 7) << 4))) + ((lane & 1) << 3);

    // consume: A from X-slot row c16; B from U-LDS row wk*16+c16
    const int aro  = c16 * 512;
    const int aswz = (c16 & 7) << 4;
    const int ukl  = wk * 16 + c16;
    const int uob  = ukl * 512;
    const int uswz = (ukl & 7) << 4;

    // Yt write offsets (pair 0 / pair 1)
    const int ytr  = ukl;                // Yt row = k'loc = wk*16+c16
    const int ytk  = (ytr & 7) << 4;
    const int ytw0 = ytr * 128 + (((0 * 64) + wj * 32 + g8) ^ ytk);
    const int ytw1 = ytr * 128 + (((1 * 64) + wj * 32 + g8) ^ ytk);

    // stage-B Yt read offsets (r9)
    const int ybA = (wn * 32 + c16) * 128;
    const int ybB = (wn * 32 + 16 + c16) * 128;
    const int ysA = ((wn * 32 + c16) & 7) << 4;
    const int ysB = ((wn * 32 + 16 + c16) & 7) << 4;

    // ---- stage U-half into swizzled LDS (r3-proven) ----
    #pragma unroll
    for (int q = 0; q < 4; ++q) {
        int c    = tid + q * 512;
        int row  = c >> 5;
        int slot = c & 31;
        int ss   = slot ^ (row & 7);
        const short* sr = Urg + (size_t)(kh * 64 + row) * 256 + ss * 8;
        const short* si = Uig + (size_t)(kh * 64 + row) * 256 + ss * 8;
        *(bf16x8*)(smem + row * 512 + slot * 16)         = *(const bf16x8*)sr;
        *(bf16x8*)(smem + 32768 + row * 512 + slot * 16) = *(const bf16x8*)si;
    }

    f32x4 zero = {0.f, 0.f, 0.f, 0.f};
    f32x4 sR00 = zero, sR01 = zero, sR10 = zero, sR11 = zero;
    f32x4 sI00 = zero, sI01 = zero, sI10 = zero, sI11 = zero;
    f32x4 tr4 = zero;
    f32x4 yR = zero, yI = zero;
    bf16x8 q0r, q0i, q1r, q1i;

    // ---- prologue: stage pair-0 (slices rows 0..15 / 16..31 -> slots 0,1) ----
    {
        f32x4 a0 = *(const f32x4*)(xr + xgb + (0  + sr0) * 256 + xl4);
        f32x4 a1 = *(const f32x4*)(xr + xgb + (0  + sr1) * 256 + xl4);
        f32x4 a2 = *(const f32x4*)(xi + xgb + (0  + sr0) * 256 + xl4);
        f32x4 a3 = *(const f32x4*)(xi + xgb + (0  + sr1) * 256 + xl4);
        f32x4 b0 = *(const f32x4*)(xr + xgb + (16 + sr0) * 256 + xl4);
        f32x4 b1 = *(const f32x4*)(xr + xgb + (16 + sr1) * 256 + xl4);
        f32x4 b2 = *(const f32x4*)(xi + xgb + (16 + sr0) * 256 + xl4);
        f32x4 b3 = *(const f32x4*)(xi + xgb + (16 + sr1) * 256 + xl4);
        const int qb = (0 + wj * 16 + c16) * 256 + kk0 * 32 + g8;
        q0r = *(const bf16x8*)(Qrb + qb);
        q0i = *(const bf16x8*)(Qib + qb);
        q1r = *(const bf16x8*)(Qrb + qb + 32);
        q1i = *(const bf16x8*)(Qib + qb + 32);
        char* w0p = smem + 81920;
        char* w1p = smem + 81920 + 16384;
        *(uint2*)(w0p + wr0o)        = cvt2(a0);
        *(uint2*)(w0p + wr1o)        = cvt2(a1);
        *(uint2*)(w0p + 8192 + wr0o) = cvt2(a2);
        *(uint2*)(w0p + 8192 + wr1o) = cvt2(a3);
        *(uint2*)(w1p + wr0o)        = cvt2(b0);
        *(uint2*)(w1p + wr1o)        = cvt2(b1);
        *(uint2*)(w1p + 8192 + wr0o) = cvt2(b2);
        *(uint2*)(w1p + 8192 + wr1o) = cvt2(b3);
    }
    asm volatile("s_waitcnt lgkmcnt(0)" ::: "memory");
    __builtin_amdgcn_sched_barrier(0);
    __builtin_amdgcn_s_barrier();
    __builtin_amdgcn_sched_barrier(0);

    PAIR(0, 0);
    PAIR(1, 0);
    STAGEB_PASS(0);
    PAIR(2, 0);
    PAIR(3, 0);
    STAGEB_PASS(1);
    PAIR(4, 0);
    PAIR(5, 0);
    STAGEB_PASS(2);
    PAIR(6, 0);
    PAIR(7, 1);
    STAGEB_KS(3, 0);
    STAGEB_KS(3, 1);

    // ---- trace: each diag j counted exactly once; reduce over 8 waves ----
    float loc = ((c16 >> 2) == g4) ? tr4[c16 & 3] : 0.f;
    #pragma unroll
    for (int o = 32; o > 0; o >>= 1) loc += __shfl_xor(loc, o);
    __syncthreads();                      // Yt dead; reuse for reduction
    float* red = (float*)(smem + 65536);
    if (lane == 0) red[w] = loc;
    __syncthreads();
    float tr = red[0] + red[1] + red[2] + red[3] +
               red[4] + red[5] + red[6] + red[7];

    float s     = sv[0];
    float inv   = s / tr;
    float onems = 1.f - s;
    float* outr = out + (size_t)b * 16384;
    float* outi = out + 8388608 + (size_t)b * 16384;

    #define EPI(SRV, SIV, MT, NT) do {                                          \
        int colc = kh * 64 + wn * 32 + (NT) * 16 + c16;                         \
        _Pragma("unroll")                                                       \
        for (int r = 0; r < 4; ++r) {                                           \
            int row = wm * 32 + (MT) * 16 + g4 * 4 + r;                         \
            float vr = SRV[r] * inv;                                            \
            if (row == colc) vr += onems * pv[row];                             \
            outr[row * 128 + colc] = vr;                                        \
            outi[row * 128 + colc] = SIV[r] * inv;                              \
        }                                                                       \
    } while (0)

    EPI(sR00, sI00, 0, 0);
    EPI(sR01, sI01, 0, 1);
    EPI(sR10, sI10, 1, 0);
    EPI(sR11, sI11, 1, 1);
    #undef EPI
}

extern "C" void kernel_launch(void* const* d_in, const int* in_sizes, int n_in,
                              void* d_out, int out_size, void* d_ws, size_t ws_size,
                              hipStream_t stream) {
    (void)in_sizes; (void)n_in; (void)out_size; (void)ws_size;
    const float* xr = (const float*)d_in[0];
    const float* xi = (const float*)d_in[1];
    const float* wt = (const float*)d_in[2];
    const float* rw = (const float*)d_in[3];
    const float* lm = (const float*)d_in[4];

    short* Ur  = (short*)d_ws;                        // 64 KB row-major bf16
    short* Ui  = (short*)((char*)d_ws + 65536);       // 64 KB
    short* Upr = (short*)((char*)d_ws + 131072);      // 64 KB packed frags
    short* Upi = (short*)((char*)d_ws + 196608);      // 64 KB
    short* Qrb = (short*)((char*)d_ws + 262144);      // 128 KB row-major bf16
    short* Qib = (short*)((char*)d_ws + 393216);      // 128 KB
    float* pv  = (float*)((char*)d_ws + 524288);      // 128 f32
    float* sv  = pv + 128;                            // 1 f32
    float* o   = (float*)d_out;

    qprep_u<<<dim3(128), dim3(256), 0, stream>>>(wt, Ur, Ui, Upr, Upi);
    qprep_ps<<<dim3(1), dim3(64), 0, stream>>>(rw, lm, pv, sv);
    qprep_q<<<dim3(256), dim3(256), 0, stream>>>(wt, Qrb, Qib);
    qfused<<<dim3(1024), dim3(512), 0, stream>>>(xr, xi, Ur, Ui, Upr, Upi,
                                                 Qrb, Qib, pv, sv, o);
}

// Round 15
// 163.735 us; speedup vs baseline: 1.8475x; 1.0458x over previous
//
#include <hip/hip_runtime.h>
#include <hip/hip_bf16.h>

// QDense: out = s * (U X U^H)[:128,:128] / tr + (1-s) * diag(softmax(rand_w))
// B=512, D=256, O=128.
// Round-15 = round-14 (171us best) + two fixes:
//   1. 2-pair-ahead X prefetch: loads for pair Q+2 issued at pair Q, held in
//      named regs, ds_written at pair Q+1 (first use = one full pair later ->
//      HBM latency fully covered; r14 awaited loads ~150cy after issue).
//   2. XCD sibling pairing: remap bx so blocks (b,kh=0) and (b,kh=1) share
//      bx%8 (same XCD) -> sibling's X reads hit L2, halving HBM fetch.
// Structure otherwise r14: full-row 1KB coalesced X loads, f32->bf16 at
// staging, 4-slot X ring (2 pairs), U-half swizzled LDS, packed-U stage B,
// 1 barrier/pair + lgkmcnt only (vmcnt stays counted).
// LDS: U 64K + Yt 16K + X-ring 64K = 144KB -> 1 block/CU.
// 1024 blocks, 512 thr.

typedef __attribute__((ext_vector_type(4))) float f32x4;
typedef __attribute__((ext_vector_type(8))) short bf16x8;

static __device__ __forceinline__ short f2bf(float f) {   // prep kernels only
    unsigned u = __float_as_uint(f);
    u += 0x7fffu + ((u >> 16) & 1u);
    return (short)(u >> 16);
}

static __device__ __forceinline__ unsigned cvtpk2(float lo, float hi) {
    union { __hip_bfloat162 h; unsigned u; } c;
    c.h = __float22bfloat162_rn(float2{lo, hi});
    return c.u;
}

static __device__ __forceinline__ uint2 cvt2(f32x4 v) {
    uint2 r;
    r.x = cvtpk2(v[0], v[1]);
    r.y = cvtpk2(v[2], v[3]);
    return r;
}

static __device__ __forceinline__ f32x4 mfma16(bf16x8 a, bf16x8 b, f32x4 c) {
    return __builtin_amdgcn_mfma_f32_16x16x32_bf16(a, b, c, 0, 0, 0);
}

// ---- prep: U -> bf16 row-major (Ur/Ui) and fragment-packed (Upr/Upi) ----
__global__ void qprep_u(const float* __restrict__ wt,
                        short* __restrict__ Ur,  short* __restrict__ Ui,
                        short* __restrict__ Upr, short* __restrict__ Upi) {
    int idx = blockIdx.x * 256 + threadIdx.x;     // j*256+k, j<128
    int j = idx >> 8, k = idx & 255;
    float2 v = ((const float2*)wt)[idx];
    short br = f2bf(v.x), bi = f2bf(v.y);
    Ur[idx] = br;
    Ui[idx] = bi;
    int g = j >> 4, s = k >> 5;
    int lanep = (j & 15) | (((k >> 3) & 3) << 4);
    int p = ((g * 8 + s) * 64 + lanep) * 8 + (k & 7);
    Upr[p] = br;
    Upi[p] = bi;
}

__global__ void qprep_ps(const float* __restrict__ rw, const float* __restrict__ lm,
                         float* __restrict__ pv, float* __restrict__ sv) {
    int t = threadIdx.x;
    float w0 = rw[t], w1 = rw[t + 64];
    float m = fmaxf(w0, w1);
    #pragma unroll
    for (int o = 32; o > 0; o >>= 1) m = fmaxf(m, __shfl_xor(m, o));
    float e0 = expf(w0 - m), e1 = expf(w1 - m);
    float ss = e0 + e1;
    #pragma unroll
    for (int o = 32; o > 0; o >>= 1) ss += __shfl_xor(ss, o);
    pv[t] = e0 / ss;
    pv[t + 64] = e1 / ss;
    if (t == 0) sv[0] = 1.f / (1.f + expf(-lm[0]));
}

__global__ void qprep_q(const float* __restrict__ wt,
                        short* __restrict__ Qrb, short* __restrict__ Qib) {
    int j = blockIdx.x;
    int k = threadIdx.x;
    float ar = 0.f, ai = 0.f;
    for (int i = 0; i < 128; ++i) {
        float2 uk = ((const float2*)wt)[i * 256 + k];
        float2 uj = ((const float2*)wt)[i * 256 + j];
        ar += uk.x * uj.x + uk.y * uj.y;
        ai += uk.x * uj.y - uk.y * uj.x;
    }
    Qrb[j * 256 + k] = f2bf(ar);
    Qib[j * 256 + k] = f2bf(ai);
}

#define PB(Q) ((Q) * 32)                 // pair row base (rows in batch)

// ---- consume one rotated ks step (KS, TR: 0 none / 1 q0 / 2 q1) ----
#define CONS(KS, TR) do {                                                       \
    const int ke = ((KS) + kk0) & 7;                                            \
    const int ko = ke * 64 + g16;                                               \
    bf16x8 axr = *(const bf16x8*)(xsp + aro + (ko ^ aswz));                     \
    bf16x8 axi = *(const bf16x8*)(xsp + 8192 + aro + (ko ^ aswz));              \
    bf16x8 bur = *(const bf16x8*)(smem + uob + (ko ^ uswz));                    \
    bf16x8 bui = *(const bf16x8*)(smem + 32768 + uob + (ko ^ uswz));            \
    bf16x8 axrn = axr ^ (short)0x8000;                                          \
    yR = mfma16(axr,  bur, yR);                                                 \
    yR = mfma16(axi,  bui, yR);                                                 \
    yI = mfma16(axi,  bur, yI);                                                 \
    yI = mfma16(axrn, bui, yI);                                                 \
    if ((TR) == 1) {                                                            \
        bf16x8 axin = axi ^ (short)0x8000;                                      \
        tr4 = mfma16(axr,  q0r, tr4);                                           \
        tr4 = mfma16(axin, q0i, tr4);                                           \
    }                                                                           \
    if ((TR) == 2) {                                                            \
        bf16x8 axin = axi ^ (short)0x8000;                                      \
        tr4 = mfma16(axr,  q1r, tr4);                                           \
        tr4 = mfma16(axin, q1i, tr4);                                           \
    }                                                                           \
} while (0)

// ---- one phase-pair (Q literal 0..7) ----
// ds_write pair Q+1 (regs loaded at pair Q-1) -> 1 full pair of vmcnt cover;
// issue pair Q+2 loads; consume pair Q; 1 barrier.
#define PAIR(Q) do {                                                            \
    const char* xsp = smem + 81920 + ((Q) & 1) * 32768 + wj16k;                 \
    if ((Q) < 7) {                                                              \
        char* wp0 = smem + 81920 + (((Q) + 1) & 1) * 32768;                     \
        *(uint2*)(wp0 + wr0o)        = cvt2(pA0);                               \
        *(uint2*)(wp0 + wr1o)        = cvt2(pA1);                               \
        *(uint2*)(wp0 + 8192 + wr0o) = cvt2(pA2);                               \
        *(uint2*)(wp0 + 8192 + wr1o) = cvt2(pA3);                               \
        char* wp1 = wp0 + 16384;                                                \
        *(uint2*)(wp1 + wr0o)        = cvt2(pB0);                               \
        *(uint2*)(wp1 + wr1o)        = cvt2(pB1);                               \
        *(uint2*)(wp1 + 8192 + wr0o) = cvt2(pB2);                               \
        *(uint2*)(wp1 + 8192 + wr1o) = cvt2(pB3);                               \
    }                                                                           \
    if ((Q) < 6) {                                                              \
        const int r0 = (PB((Q) + 2) + sr0) * 256 + xl4;                         \
        const int r1 = (PB((Q) + 2) + sr1) * 256 + xl4;                         \
        pA0 = *(const f32x4*)(xr + xgb + r0);                                   \
        pA1 = *(const f32x4*)(xr + xgb + r1);                                   \
        pA2 = *(const f32x4*)(xi + xgb + r0);                                   \
        pA3 = *(const f32x4*)(xi + xgb + r1);                                   \
        const int r2 = (PB((Q) + 2) + 16 + sr0) * 256 + xl4;                    \
        const int r3 = (PB((Q) + 2) + 16 + sr1) * 256 + xl4;                    \
        pB0 = *(const f32x4*)(xr + xgb + r2);                                   \
        pB1 = *(const f32x4*)(xr + xgb + r3);                                   \
        pB2 = *(const f32x4*)(xi + xgb + r2);                                   \
        pB3 = *(const f32x4*)(xi + xgb + r3);                                   \
    }                                                                           \
    __builtin_amdgcn_sched_barrier(0);                                          \
    CONS(0, 1);                                                                 \
    CONS(1, 2);                                                                 \
    CONS(2, 0);                                                                 \
    CONS(3, 0);                                                                 \
    if ((Q) < 7) {   /* Q-trace prefetch for pair Q+1 (overwrites q0/q1) */     \
        const int qb = (PB((Q) + 1) + wj * 16 + c16) * 256 + kk0 * 32 + g8;     \
        q0r = *(const bf16x8*)(Qrb + qb);                                       \
        q0i = *(const bf16x8*)(Qib + qb);                                       \
        q1r = *(const bf16x8*)(Qrb + qb + 32);                                  \
        q1i = *(const bf16x8*)(Qib + qb + 32);                                  \
    }                                                                           \
    __builtin_amdgcn_sched_barrier(0);                                          \
    CONS(4, 0);                                                                 \
    CONS(5, 0);                                                                 \
    CONS(6, 0);                                                                 \
    CONS(7, 0);                                                                 \
    {                                                                           \
        const int yw = ((Q) & 1) ? ytw1 : ytw0;                                 \
        *(uint2*)(smem + 65536 + yw) = cvt2(yR);                                \
        *(uint2*)(smem + 73728 + yw) = cvt2(yI);                                \
    }                                                                           \
    yR = zero; yI = zero;                                                       \
    asm volatile("s_waitcnt lgkmcnt(0)" ::: "memory");                          \
    __builtin_amdgcn_sched_barrier(0);                                          \
    __builtin_amdgcn_s_barrier();                                               \
    __builtin_amdgcn_sched_barrier(0);                                          \
} while (0)

// ---- stage B (packed-U A-operand; Yt reads r9-proven) ----
#define STAGEB_KS(JT, KS2) do {                                                 \
    const int s2 = (JT) * 2 + (KS2);                                            \
    bf16x8 aur0 = *(const bf16x8*)(Upr + ((wm * 2 + 0) * 8 + s2) * 512 + l8);   \
    bf16x8 aui0 = *(const bf16x8*)(Upi + ((wm * 2 + 0) * 8 + s2) * 512 + l8);   \
    bf16x8 aur1 = *(const bf16x8*)(Upr + ((wm * 2 + 1) * 8 + s2) * 512 + l8);   \
    bf16x8 aui1 = *(const bf16x8*)(Upi + ((wm * 2 + 1) * 8 + s2) * 512 + l8);   \
    bf16x8 auin0 = aui0 ^ (short)0x8000;                                        \
    bf16x8 auin1 = aui1 ^ (short)0x8000;                                        \
    {                                                                           \
        const int off = ybA + (((KS2) * 64 + g16) ^ ysA);                       \
        bf16x8 byr = *(const bf16x8*)(smem + 65536 + off);                      \
        bf16x8 byi = *(const bf16x8*)(smem + 73728 + off);                      \
        sR00 = mfma16(aur0,  byr, sR00); sR00 = mfma16(auin0, byi, sR00);       \
        sI00 = mfma16(aui0,  byr, sI00); sI00 = mfma16(aur0,  byi, sI00);       \
        sR10 = mfma16(aur1,  byr, sR10); sR10 = mfma16(auin1, byi, sR10);       \
        sI10 = mfma16(aui1,  byr, sI10); sI10 = mfma16(aur1,  byi, sI10);       \
    }                                                                           \
    {                                                                           \
        const int off = ybB + (((KS2) * 64 + g16) ^ ysB);                       \
        bf16x8 byr = *(const bf16x8*)(smem + 65536 + off);                      \
        bf16x8 byi = *(const bf16x8*)(smem + 73728 + off);                      \
        sR01 = mfma16(aur0,  byr, sR01); sR01 = mfma16(auin0, byi, sR01);       \
        sI01 = mfma16(aui0,  byr, sI01); sI01 = mfma16(aur0,  byi, sI01);       \
        sR11 = mfma16(aur1,  byr, sR11); sR11 = mfma16(auin1, byi, sR11);       \
        sI11 = mfma16(aui1,  byr, sI11); sI11 = mfma16(aur1,  byi, sI11);       \
    }                                                                           \
} while (0)

#define STAGEB_PASS(JT) do {                                                    \
    STAGEB_KS(JT, 0);                                                           \
    STAGEB_KS(JT, 1);                                                           \
    asm volatile("s_waitcnt lgkmcnt(0)" ::: "memory");                          \
    __builtin_amdgcn_sched_barrier(0);                                          \
    __builtin_amdgcn_s_barrier();      /* Yt reads done before next writes */   \
    __builtin_amdgcn_sched_barrier(0);                                          \
} while (0)

// ---- main fused kernel ----
__global__ __launch_bounds__(512, 1) void qfused(
    const float* __restrict__ xr, const float* __restrict__ xi,
    const short* __restrict__ Urg, const short* __restrict__ Uig,
    const short* __restrict__ Upr, const short* __restrict__ Upi,
    const short* __restrict__ Qrb, const short* __restrict__ Qib,
    const float* __restrict__ pv, const float* __restrict__ sv,
    float* __restrict__ out)
{
    // [0,65536) U-half swizzled (R 0, I 32768); [65536,81920) Yt (R/I);
    // [81920,147456) X ring: 4 slots x (R[16x512B] + I at +8192).
    __shared__ __align__(16) char smem[147456];

    const int bx   = blockIdx.x;
    // XCD sibling pairing: batch b's two kh-blocks share bx%8 (same XCD).
    const int b    = ((bx >> 4) << 3) | (bx & 7);
    const int kh   = (bx >> 3) & 1;
    const int tid  = threadIdx.x;
    const int lane = tid & 63;
    const int w    = tid >> 6;
    const int c16  = lane & 15;
    const int g4   = lane >> 4;
    const int g8   = g4 * 8;
    const int g16  = g4 * 16;
    const int l8   = lane * 8;

    const int wj    = w >> 2;            // my slice within pair (0/1)
    const int wk    = w & 3;             // my k'-group
    const int kk0   = wk * 2;            // my trace-ks base (rotation)
    const int wj16k = wj * 16384;
    const int wm    = w >> 1;            // stage-B row-quarter
    const int wn    = w & 1;             // stage-B k'-half-of-half

    // X staging: wave stages slot-rows {w*2, w*2+1}; lane covers bytes l*16.
    const int sr0 = w * 2, sr1 = w * 2 + 1;
    const int xl4 = lane * 4;            // float offset within row
    const int xgb = b << 16;
    const int wr0o = sr0 * 512 + ((((lane >> 1) << 4) ^ ((sr0 & 7) << 4))) + ((lane & 1) << 3);
    const int wr1o = sr1 * 512 + ((((lane >> 1) << 4) ^ ((sr1 & 7) << 4))) + ((lane & 1) << 3);

    // consume: A from X-slot row c16; B from U-LDS row wk*16+c16
    const int aro  = c16 * 512;
    const int aswz = (c16 & 7) << 4;
    const int ukl  = wk * 16 + c16;
    const int uob  = ukl * 512;
    const int uswz = (ukl & 7) << 4;

    // Yt write offsets (pair 0 / pair 1 within a pass)
    const int ytr  = ukl;
    const int ytk  = (ytr & 7) << 4;
    const int ytw0 = ytr * 128 + ((wj * 32 + g8) ^ ytk);
    const int ytw1 = ytr * 128 + ((64 + wj * 32 + g8) ^ ytk);

    // stage-B Yt read offsets
    const int ybA = (wn * 32 + c16) * 128;
    const int ybB = (wn * 32 + 16 + c16) * 128;
    const int ysA = ((wn * 32 + c16) & 7) << 4;
    const int ysB = ((wn * 32 + 16 + c16) & 7) << 4;

    // ---- stage U-half into swizzled LDS (r3-proven) ----
    #pragma unroll
    for (int q = 0; q < 4; ++q) {
        int c    = tid + q * 512;
        int row  = c >> 5;
        int slot = c & 31;
        int ss   = slot ^ (row & 7);
        const short* sr = Urg + (size_t)(kh * 64 + row) * 256 + ss * 8;
        const short* si = Uig + (size_t)(kh * 64 + row) * 256 + ss * 8;
        *(bf16x8*)(smem + row * 512 + slot * 16)         = *(const bf16x8*)sr;
        *(bf16x8*)(smem + 32768 + row * 512 + slot * 16) = *(const bf16x8*)si;
    }

    f32x4 zero = {0.f, 0.f, 0.f, 0.f};
    f32x4 sR00 = zero, sR01 = zero, sR10 = zero, sR11 = zero;
    f32x4 sI00 = zero, sI01 = zero, sI10 = zero, sI11 = zero;
    f32x4 tr4 = zero;
    f32x4 yR = zero, yI = zero;
    bf16x8 q0r, q0i, q1r, q1i;
    f32x4 pA0, pA1, pA2, pA3;            // held loads for next pair, slice 0
    f32x4 pB0, pB1, pB2, pB3;            // held loads for next pair, slice 1

    // ---- prologue: pair-0 direct-stage; pair-1 into held regs; Q(pair0) ----
    {
        const int r0 = (PB(0) + sr0) * 256 + xl4;
        const int r1 = (PB(0) + sr1) * 256 + xl4;
        const int r2 = (PB(0) + 16 + sr0) * 256 + xl4;
        const int r3 = (PB(0) + 16 + sr1) * 256 + xl4;
        f32x4 a0 = *(const f32x4*)(xr + xgb + r0);
        f32x4 a1 = *(const f32x4*)(xr + xgb + r1);
        f32x4 a2 = *(const f32x4*)(xi + xgb + r0);
        f32x4 a3 = *(const f32x4*)(xi + xgb + r1);
        f32x4 b0 = *(const f32x4*)(xr + xgb + r2);
        f32x4 b1 = *(const f32x4*)(xr + xgb + r3);
        f32x4 b2 = *(const f32x4*)(xi + xgb + r2);
        f32x4 b3 = *(const f32x4*)(xi + xgb + r3);
        const int r4 = (PB(1) + sr0) * 256 + xl4;
        const int r5 = (PB(1) + sr1) * 256 + xl4;
        const int r6 = (PB(1) + 16 + sr0) * 256 + xl4;
        const int r7 = (PB(1) + 16 + sr1) * 256 + xl4;
        pA0 = *(const f32x4*)(xr + xgb + r4);
        pA1 = *(const f32x4*)(xr + xgb + r5);
        pA2 = *(const f32x4*)(xi + xgb + r4);
        pA3 = *(const f32x4*)(xi + xgb + r5);
        pB0 = *(const f32x4*)(xr + xgb + r6);
        pB1 = *(const f32x4*)(xr + xgb + r7);
        pB2 = *(const f32x4*)(xi + xgb + r6);
        pB3 = *(const f32x4*)(xi + xgb + r7);
        const int qb = (PB(0) + wj * 16 + c16) * 256 + kk0 * 32 + g8;
        q0r = *(const bf16x8*)(Qrb + qb);
        q0i = *(const bf16x8*)(Qib + qb);
        q1r = *(const bf16x8*)(Qrb + qb + 32);
        q1i = *(const bf16x8*)(Qib + qb + 32);
        char* w0p = smem + 81920;
        char* w1p = smem + 81920 + 16384;
        *(uint2*)(w0p + wr0o)        = cvt2(a0);
        *(uint2*)(w0p + wr1o)        = cvt2(a1);
        *(uint2*)(w0p + 8192 + wr0o) = cvt2(a2);
        *(uint2*)(w0p + 8192 + wr1o) = cvt2(a3);
        *(uint2*)(w1p + wr0o)        = cvt2(b0);
        *(uint2*)(w1p + wr1o)        = cvt2(b1);
        *(uint2*)(w1p + 8192 + wr0o) = cvt2(b2);
        *(uint2*)(w1p + 8192 + wr1o) = cvt2(b3);
    }
    asm volatile("s_waitcnt lgkmcnt(0)" ::: "memory");
    __builtin_amdgcn_sched_barrier(0);
    __builtin_amdgcn_s_barrier();
    __builtin_amdgcn_sched_barrier(0);

    PAIR(0);
    PAIR(1);
    STAGEB_PASS(0);
    PAIR(2);
    PAIR(3);
    STAGEB_PASS(1);
    PAIR(4);
    PAIR(5);
    STAGEB_PASS(2);
    PAIR(6);
    PAIR(7);
    STAGEB_KS(3, 0);
    STAGEB_KS(3, 1);

    // ---- trace: each diag j counted exactly once; reduce over 8 waves ----
    float loc = ((c16 >> 2) == g4) ? tr4[c16 & 3] : 0.f;
    #pragma unroll
    for (int o = 32; o > 0; o >>= 1) loc += __shfl_xor(loc, o);
    __syncthreads();                      // Yt dead; reuse for reduction
    float* red = (float*)(smem + 65536);
    if (lane == 0) red[w] = loc;
    __syncthreads();
    float tr = red[0] + red[1] + red[2] + red[3] +
               red[4] + red[5] + red[6] + red[7];

    float s     = sv[0];
    float inv   = s / tr;
    float onems = 1.f - s;
    float* outr = out + (size_t)b * 16384;
    float* outi = out + 8388608 + (size_t)b * 16384;

    #define EPI(SRV, SIV, MT, NT) do {                                          \
        int colc = kh * 64 + wn * 32 + (NT) * 16 + c16;                         \
        _Pragma("unroll")                                                       \
        for (int r = 0; r < 4; ++r) {                                           \
            int row = wm * 32 + (MT) * 16 + g4 * 4 + r;                         \
            float vr = SRV[r] * inv;                                            \
            if (row == colc) vr += onems * pv[row];                             \
            outr[row * 128 + colc] = vr;                                        \
            outi[row * 128 + colc] = SIV[r] * inv;                              \
        }                                                                       \
    } while (0)

    EPI(sR00, sI00, 0, 0);
    EPI(sR01, sI01, 0, 1);
    EPI(sR10, sI10, 1, 0);
    EPI(sR11, sI11, 1, 1);
    #undef EPI
}

extern "C" void kernel_launch(void* const* d_in, const int* in_sizes, int n_in,
                              void* d_out, int out_size, void* d_ws, size_t ws_size,
                              hipStream_t stream) {
    (void)in_sizes; (void)n_in; (void)out_size; (void)ws_size;
    const float* xr = (const float*)d_in[0];
    const float* xi = (const float*)d_in[1];
    const float* wt = (const float*)d_in[2];
    const float* rw = (const float*)d_in[3];
    const float* lm = (const float*)d_in[4];

    short* Ur  = (short*)d_ws;                        // 64 KB row-major bf16
    short* Ui  = (short*)((char*)d_ws + 65536);       // 64 KB
    short* Upr = (short*)((char*)d_ws + 131072);      // 64 KB packed frags
    short* Upi = (short*)((char*)d_ws + 196608);      // 64 KB
    short* Qrb = (short*)((char*)d_ws + 262144);      // 128 KB row-major bf16
    short* Qib = (short*)((char*)d_ws + 393216);      // 128 KB
    float* pv  = (float*)((char*)d_ws + 524288);      // 128 f32
    float* sv  = pv + 128;                            // 1 f32
    float* o   = (float*)d_out;

    qprep_u<<<dim3(128), dim3(256), 0, stream>>>(wt, Ur, Ui, Upr, Upi);
    qprep_ps<<<dim3(1), dim3(64), 0, stream>>>(rw, lm, pv, sv);
    qprep_q<<<dim3(256), dim3(256), 0, stream>>>(wt, Qrb, Qib);
    qfused<<<dim3(1024), dim3(512), 0, stream>>>(xr, xi, Ur, Ui, Upr, Upi,
                                                 Qrb, Qib, pv, sv, o);
}

// Round 16
// 157.748 us; speedup vs baseline: 1.9176x; 1.0380x over previous
//
#include <hip/hip_runtime.h>
#include <hip/hip_bf16.h>

// QDense: out = s * (U X U^H)[:128,:128] / tr + (1-s) * diag(softmax(rand_w))
// B=512, D=256, O=128.
// Round-16 = round-15 (163us best) with the spill removed:
//   - trace via elementwise VALU dot on the HELD STAGING REGISTERS
//     (tr = sum Xr*Qr - Xi*Qi over all elements; each X element is staged
//     exactly once per block while still f32 in regs).  Deletes the 16-reg
//     Q MFMA ring + 4 AGPR tr4 + 2 MFMAs/step + ks rotation -> ~20 regs
//     freed so the 2-pair-ahead X prefetch fits WITHOUT scratch spill.
// Everything else r15: full-row 1KB coalesced X loads, f32->bf16 at staging,
// 4-slot X ring, 2-pair-ahead held-reg prefetch, XCD sibling pairing,
// U-half swizzled LDS, packed-U stage B, 1 barrier/pair + lgkmcnt only.
// LDS: U 64K + Yt 16K + X-ring 64K = 144KB -> 1 block/CU.  1024 blocks, 512 thr.

typedef __attribute__((ext_vector_type(4))) float f32x4;
typedef __attribute__((ext_vector_type(8))) short bf16x8;

static __device__ __forceinline__ short f2bf(float f) {   // prep kernels only
    unsigned u = __float_as_uint(f);
    u += 0x7fffu + ((u >> 16) & 1u);
    return (short)(u >> 16);
}

static __device__ __forceinline__ float b2f(unsigned short h) {
    return __uint_as_float(((unsigned)h) << 16);
}

static __device__ __forceinline__ unsigned cvtpk2(float lo, float hi) {
    union { __hip_bfloat162 h; unsigned u; } c;
    c.h = __float22bfloat162_rn(float2{lo, hi});
    return c.u;
}

static __device__ __forceinline__ uint2 cvt2(f32x4 v) {
    uint2 r;
    r.x = cvtpk2(v[0], v[1]);
    r.y = cvtpk2(v[2], v[3]);
    return r;
}

static __device__ __forceinline__ f32x4 mfma16(bf16x8 a, bf16x8 b, f32x4 c) {
    return __builtin_amdgcn_mfma_f32_16x16x32_bf16(a, b, c, 0, 0, 0);
}

// ---- prep: U -> bf16 row-major (Ur/Ui) and fragment-packed (Upr/Upi) ----
__global__ void qprep_u(const float* __restrict__ wt,
                        short* __restrict__ Ur,  short* __restrict__ Ui,
                        short* __restrict__ Upr, short* __restrict__ Upi) {
    int idx = blockIdx.x * 256 + threadIdx.x;     // j*256+k, j<128
    int j = idx >> 8, k = idx & 255;
    float2 v = ((const float2*)wt)[idx];
    short br = f2bf(v.x), bi = f2bf(v.y);
    Ur[idx] = br;
    Ui[idx] = bi;
    int g = j >> 4, s = k >> 5;
    int lanep = (j & 15) | (((k >> 3) & 3) << 4);
    int p = ((g * 8 + s) * 64 + lanep) * 8 + (k & 7);
    Upr[p] = br;
    Upi[p] = bi;
}

__global__ void qprep_ps(const float* __restrict__ rw, const float* __restrict__ lm,
                         float* __restrict__ pv, float* __restrict__ sv) {
    int t = threadIdx.x;
    float w0 = rw[t], w1 = rw[t + 64];
    float m = fmaxf(w0, w1);
    #pragma unroll
    for (int o = 32; o > 0; o >>= 1) m = fmaxf(m, __shfl_xor(m, o));
    float e0 = expf(w0 - m), e1 = expf(w1 - m);
    float ss = e0 + e1;
    #pragma unroll
    for (int o = 32; o > 0; o >>= 1) ss += __shfl_xor(ss, o);
    pv[t] = e0 / ss;
    pv[t + 64] = e1 / ss;
    if (t == 0) sv[0] = 1.f / (1.f + expf(-lm[0]));
}

// Q[j][k] = P[k][j], P = U_sub^H U_sub  (bf16, row-major)
__global__ void qprep_q(const float* __restrict__ wt,
                        short* __restrict__ Qrb, short* __restrict__ Qib) {
    int j = blockIdx.x;
    int k = threadIdx.x;
    float ar = 0.f, ai = 0.f;
    for (int i = 0; i < 128; ++i) {
        float2 uk = ((const float2*)wt)[i * 256 + k];
        float2 uj = ((const float2*)wt)[i * 256 + j];
        ar += uk.x * uj.x + uk.y * uj.y;
        ai += uk.x * uj.y - uk.y * uj.x;
    }
    Qrb[j * 256 + k] = f2bf(ar);
    Qib[j * 256 + k] = f2bf(ai);
}

#define PB(Q) ((Q) * 32)                 // pair row base (rows in batch)

// ---- elementwise trace dot on held staging regs (rows RB+sr0, RB+sr1) ----
// tracc += sum Xr*Qr - Xi*Qi over the lane's 2x4 f32 chunk of each plane.
#define TRDOT(RB, A0, A1, A2, A3) do {                                          \
    const int qo0 = ((RB) + sr0) * 256 + xl4;                                   \
    const int qo1 = ((RB) + sr1) * 256 + xl4;                                   \
    ushort4 hr0 = *(const ushort4*)(Qrb + qo0);                                 \
    ushort4 hr1 = *(const ushort4*)(Qrb + qo1);                                 \
    ushort4 hi0 = *(const ushort4*)(Qib + qo0);                                 \
    ushort4 hi1 = *(const ushort4*)(Qib + qo1);                                 \
    tracc += A0[0]*b2f(hr0.x) + A0[1]*b2f(hr0.y)                                \
           + A0[2]*b2f(hr0.z) + A0[3]*b2f(hr0.w);                               \
    tracc += A1[0]*b2f(hr1.x) + A1[1]*b2f(hr1.y)                                \
           + A1[2]*b2f(hr1.z) + A1[3]*b2f(hr1.w);                               \
    tracc -= A2[0]*b2f(hi0.x) + A2[1]*b2f(hi0.y)                                \
           + A2[2]*b2f(hi0.z) + A2[3]*b2f(hi0.w);                               \
    tracc -= A3[0]*b2f(hi1.x) + A3[1]*b2f(hi1.y)                                \
           + A3[2]*b2f(hi1.z) + A3[3]*b2f(hi1.w);                               \
} while (0)

// ---- consume one ks step ----
#define CONS(KS) do {                                                           \
    const int ko = (KS) * 64 + g16;                                             \
    bf16x8 axr = *(const bf16x8*)(xsp + aro + (ko ^ aswz));                     \
    bf16x8 axi = *(const bf16x8*)(xsp + 8192 + aro + (ko ^ aswz));              \
    bf16x8 bur = *(const bf16x8*)(smem + uob + (ko ^ uswz));                    \
    bf16x8 bui = *(const bf16x8*)(smem + 32768 + uob + (ko ^ uswz));            \
    bf16x8 axrn = axr ^ (short)0x8000;                                          \
    yR = mfma16(axr,  bur, yR);                                                 \
    yR = mfma16(axi,  bui, yR);                                                 \
    yI = mfma16(axi,  bur, yI);                                                 \
    yI = mfma16(axrn, bui, yI);                                                 \
} while (0)

// ---- one phase-pair (Q literal 0..7) ----
// ds_write pair Q+1 (regs loaded at pair Q-1) + trace-dot them;
// issue pair Q+2 loads; consume pair Q; 1 barrier.
#define PAIR(Q) do {                                                            \
    const char* xsp = smem + 81920 + ((Q) & 1) * 32768 + wj16k;                 \
    if ((Q) < 7) {                                                              \
        char* wp0 = smem + 81920 + (((Q) + 1) & 1) * 32768;                     \
        *(uint2*)(wp0 + wr0o)        = cvt2(pA0);                               \
        *(uint2*)(wp0 + wr1o)        = cvt2(pA1);                               \
        *(uint2*)(wp0 + 8192 + wr0o) = cvt2(pA2);                               \
        *(uint2*)(wp0 + 8192 + wr1o) = cvt2(pA3);                               \
        char* wp1 = wp0 + 16384;                                                \
        *(uint2*)(wp1 + wr0o)        = cvt2(pB0);                               \
        *(uint2*)(wp1 + wr1o)        = cvt2(pB1);                               \
        *(uint2*)(wp1 + 8192 + wr0o) = cvt2(pB2);                               \
        *(uint2*)(wp1 + 8192 + wr1o) = cvt2(pB3);                               \
        TRDOT(PB((Q) + 1),      pA0, pA1, pA2, pA3);                            \
        TRDOT(PB((Q) + 1) + 16, pB0, pB1, pB2, pB3);                            \
    }                                                                           \
    if ((Q) < 6) {                                                              \
        const int r0 = (PB((Q) + 2) + sr0) * 256 + xl4;                         \
        const int r1 = (PB((Q) + 2) + sr1) * 256 + xl4;                         \
        pA0 = *(const f32x4*)(xr + xgb + r0);                                   \
        pA1 = *(const f32x4*)(xr + xgb + r1);                                   \
        pA2 = *(const f32x4*)(xi + xgb + r0);                                   \
        pA3 = *(const f32x4*)(xi + xgb + r1);                                   \
        const int r2 = (PB((Q) + 2) + 16 + sr0) * 256 + xl4;                    \
        const int r3 = (PB((Q) + 2) + 16 + sr1) * 256 + xl4;                    \
        pB0 = *(const f32x4*)(xr + xgb + r2);                                   \
        pB1 = *(const f32x4*)(xr + xgb + r3);                                   \
        pB2 = *(const f32x4*)(xi + xgb + r2);                                   \
        pB3 = *(const f32x4*)(xi + xgb + r3);                                   \
    }                                                                           \
    __builtin_amdgcn_sched_barrier(0);                                          \
    CONS(0); CONS(1); CONS(2); CONS(3);                                         \
    __builtin_amdgcn_sched_barrier(0);                                          \
    CONS(4); CONS(5); CONS(6); CONS(7);                                         \
    {                                                                           \
        const int yw = ((Q) & 1) ? ytw1 : ytw0;                                 \
        *(uint2*)(smem + 65536 + yw) = cvt2(yR);                                \
        *(uint2*)(smem + 73728 + yw) = cvt2(yI);                                \
    }                                                                           \
    yR = zero; yI = zero;                                                       \
    asm volatile("s_waitcnt lgkmcnt(0)" ::: "memory");                          \
    __builtin_amdgcn_sched_barrier(0);                                          \
    __builtin_amdgcn_s_barrier();                                               \
    __builtin_amdgcn_sched_barrier(0);                                          \
} while (0)

// ---- stage B (packed-U A-operand) ----
#define STAGEB_KS(JT, KS2) do {                                                 \
    const int s2 = (JT) * 2 + (KS2);                                            \
    bf16x8 aur0 = *(const bf16x8*)(Upr + ((wm * 2 + 0) * 8 + s2) * 512 + l8);   \
    bf16x8 aui0 = *(const bf16x8*)(Upi + ((wm * 2 + 0) * 8 + s2) * 512 + l8);   \
    bf16x8 aur1 = *(const bf16x8*)(Upr + ((wm * 2 + 1) * 8 + s2) * 512 + l8);   \
    bf16x8 aui1 = *(const bf16x8*)(Upi + ((wm * 2 + 1) * 8 + s2) * 512 + l8);   \
    bf16x8 auin0 = aui0 ^ (short)0x8000;                                        \
    bf16x8 auin1 = aui1 ^ (short)0x8000;                                        \
    {                                                                           \
        const int off = ybA + (((KS2) * 64 + g16) ^ ysA);                       \
        bf16x8 byr = *(const bf16x8*)(smem + 65536 + off);                      \
        bf16x8 byi = *(const bf16x8*)(smem + 73728 + off);                      \
        sR00 = mfma16(aur0,  byr, sR00); sR00 = mfma16(auin0, byi, sR00);       \
        sI00 = mfma16(aui0,  byr, sI00); sI00 = mfma16(aur0,  byi, sI00);       \
        sR10 = mfma16(aur1,  byr, sR10); sR10 = mfma16(auin1, byi, sR10);       \
        sI10 = mfma16(aui1,  byr, sI10); sI10 = mfma16(aur1,  byi, sI10);       \
    }                                                                           \
    {                                                                           \
        const int off = ybB + (((KS2) * 64 + g16) ^ ysB);                       \
        bf16x8 byr = *(const bf16x8*)(smem + 65536 + off);                      \
        bf16x8 byi = *(const bf16x8*)(smem + 73728 + off);                      \
        sR01 = mfma16(aur0,  byr, sR01); sR01 = mfma16(auin0, byi, sR01);       \
        sI01 = mfma16(aui0,  byr, sI01); sI01 = mfma16(aur0,  byi, sI01);       \
        sR11 = mfma16(aur1,  byr, sR11); sR11 = mfma16(auin1, byi, sR11);       \
        sI11 = mfma16(aui1,  byr, sI11); sI11 = mfma16(aur1,  byi, sI11);       \
    }                                                                           \
} while (0)

#define STAGEB_PASS(JT) do {                                                    \
    STAGEB_KS(JT, 0);                                                           \
    STAGEB_KS(JT, 1);                                                           \
    asm volatile("s_waitcnt lgkmcnt(0)" ::: "memory");                          \
    __builtin_amdgcn_sched_barrier(0);                                          \
    __builtin_amdgcn_s_barrier();      /* Yt reads done before next writes */   \
    __builtin_amdgcn_sched_barrier(0);                                          \
} while (0)

// ---- main fused kernel ----
__global__ __launch_bounds__(512, 1) void qfused(
    const float* __restrict__ xr, const float* __restrict__ xi,
    const short* __restrict__ Urg, const short* __restrict__ Uig,
    const short* __restrict__ Upr, const short* __restrict__ Upi,
    const short* __restrict__ Qrb, const short* __restrict__ Qib,
    const float* __restrict__ pv, const float* __restrict__ sv,
    float* __restrict__ out)
{
    // [0,65536) U-half swizzled (R 0, I 32768); [65536,81920) Yt (R/I);
    // [81920,147456) X ring: 4 slots x (R[16x512B] + I at +8192).
    __shared__ __align__(16) char smem[147456];

    const int bx   = blockIdx.x;
    // XCD sibling pairing: batch b's two kh-blocks share bx%8 (same XCD).
    const int b    = ((bx >> 4) << 3) | (bx & 7);
    const int kh   = (bx >> 3) & 1;
    const int tid  = threadIdx.x;
    const int lane = tid & 63;
    const int w    = tid >> 6;
    const int c16  = lane & 15;
    const int g4   = lane >> 4;
    const int g8   = g4 * 8;
    const int g16  = g4 * 16;
    const int l8   = lane * 8;

    const int wj    = w >> 2;            // my slice within pair (0/1)
    const int wk    = w & 3;             // my k'-group
    const int wj16k = wj * 16384;
    const int wm    = w >> 1;            // stage-B row-quarter
    const int wn    = w & 1;             // stage-B k'-half-of-half

    // X staging: wave stages slot-rows {w*2, w*2+1}; lane covers bytes l*16.
    const int sr0 = w * 2, sr1 = w * 2 + 1;
    const int xl4 = lane * 4;            // float offset within row
    const int xgb = b << 16;
    const int wr0o = sr0 * 512 + ((((lane >> 1) << 4) ^ ((sr0 & 7) << 4))) + ((lane & 1) << 3);
    const int wr1o = sr1 * 512 + ((((lane >> 1) << 4) ^ ((sr1 & 7) << 4))) + ((lane & 1) << 3);

    // consume: A from X-slot row c16; B from U-LDS row wk*16+c16
    const int aro  = c16 * 512;
    const int aswz = (c16 & 7) << 4;
    const int ukl  = wk * 16 + c16;
    const int uob  = ukl * 512;
    const int uswz = (ukl & 7) << 4;

    // Yt write offsets (pair 0 / pair 1 within a pass)
    const int ytr  = ukl;
    const int ytk  = (ytr & 7) << 4;
    const int ytw0 = ytr * 128 + ((wj * 32 + g8) ^ ytk);
    const int ytw1 = ytr * 128 + ((64 + wj * 32 + g8) ^ ytk);

    // stage-B Yt read offsets
    const int ybA = (wn * 32 + c16) * 128;
    const int ybB = (wn * 32 + 16 + c16) * 128;
    const int ysA = ((wn * 32 + c16) & 7) << 4;
    const int ysB = ((wn * 32 + 16 + c16) & 7) << 4;

    // ---- stage U-half into swizzled LDS (r3-proven) ----
    #pragma unroll
    for (int q = 0; q < 4; ++q) {
        int c    = tid + q * 512;
        int row  = c >> 5;
        int slot = c & 31;
        int ss   = slot ^ (row & 7);
        const short* sr = Urg + (size_t)(kh * 64 + row) * 256 + ss * 8;
        const short* si = Uig + (size_t)(kh * 64 + row) * 256 + ss * 8;
        *(bf16x8*)(smem + row * 512 + slot * 16)         = *(const bf16x8*)sr;
        *(bf16x8*)(smem + 32768 + row * 512 + slot * 16) = *(const bf16x8*)si;
    }

    f32x4 zero = {0.f, 0.f, 0.f, 0.f};
    f32x4 sR00 = zero, sR01 = zero, sR10 = zero, sR11 = zero;
    f32x4 sI00 = zero, sI01 = zero, sI10 = zero, sI11 = zero;
    float tracc = 0.f;
    f32x4 yR = zero, yI = zero;
    f32x4 pA0, pA1, pA2, pA3;            // held loads for next pair, slice 0
    f32x4 pB0, pB1, pB2, pB3;            // held loads for next pair, slice 1

    // ---- prologue: pair-0 direct-stage (+trace); pair-1 into held regs ----
    {
        const int r0 = (PB(0) + sr0) * 256 + xl4;
        const int r1 = (PB(0) + sr1) * 256 + xl4;
        const int r2 = (PB(0) + 16 + sr0) * 256 + xl4;
        const int r3 = (PB(0) + 16 + sr1) * 256 + xl4;
        f32x4 a0 = *(const f32x4*)(xr + xgb + r0);
        f32x4 a1 = *(const f32x4*)(xr + xgb + r1);
        f32x4 a2 = *(const f32x4*)(xi + xgb + r0);
        f32x4 a3 = *(const f32x4*)(xi + xgb + r1);
        f32x4 b0 = *(const f32x4*)(xr + xgb + r2);
        f32x4 b1 = *(const f32x4*)(xr + xgb + r3);
        f32x4 b2 = *(const f32x4*)(xi + xgb + r2);
        f32x4 b3 = *(const f32x4*)(xi + xgb + r3);
        const int r4 = (PB(1) + sr0) * 256 + xl4;
        const int r5 = (PB(1) + sr1) * 256 + xl4;
        const int r6 = (PB(1) + 16 + sr0) * 256 + xl4;
        const int r7 = (PB(1) + 16 + sr1) * 256 + xl4;
        pA0 = *(const f32x4*)(xr + xgb + r4);
        pA1 = *(const f32x4*)(xr + xgb + r5);
        pA2 = *(const f32x4*)(xi + xgb + r4);
        pA3 = *(const f32x4*)(xi + xgb + r5);
        pB0 = *(const f32x4*)(xr + xgb + r6);
        pB1 = *(const f32x4*)(xr + xgb + r7);
        pB2 = *(const f32x4*)(xi + xgb + r6);
        pB3 = *(const f32x4*)(xi + xgb + r7);
        char* w0p = smem + 81920;
        char* w1p = smem + 81920 + 16384;
        *(uint2*)(w0p + wr0o)        = cvt2(a0);
        *(uint2*)(w0p + wr1o)        = cvt2(a1);
        *(uint2*)(w0p + 8192 + wr0o) = cvt2(a2);
        *(uint2*)(w0p + 8192 + wr1o) = cvt2(a3);
        *(uint2*)(w1p + wr0o)        = cvt2(b0);
        *(uint2*)(w1p + wr1o)        = cvt2(b1);
        *(uint2*)(w1p + 8192 + wr0o) = cvt2(b2);
        *(uint2*)(w1p + 8192 + wr1o) = cvt2(b3);
        TRDOT(PB(0),      a0, a1, a2, a3);
        TRDOT(PB(0) + 16, b0, b1, b2, b3);
    }
    asm volatile("s_waitcnt lgkmcnt(0)" ::: "memory");
    __builtin_amdgcn_sched_barrier(0);
    __builtin_amdgcn_s_barrier();
    __builtin_amdgcn_sched_barrier(0);

    PAIR(0);
    PAIR(1);
    STAGEB_PASS(0);
    PAIR(2);
    PAIR(3);
    STAGEB_PASS(1);
    PAIR(4);
    PAIR(5);
    STAGEB_PASS(2);
    PAIR(6);
    PAIR(7);
    STAGEB_KS(3, 0);
    STAGEB_KS(3, 1);

    // ---- trace: elementwise dot summed over all lanes/waves ----
    float loc = tracc;
    #pragma unroll
    for (int o = 32; o > 0; o >>= 1) loc += __shfl_xor(loc, o);
    __syncthreads();                      // Yt dead; reuse for reduction
    float* red = (float*)(smem + 65536);
    if (lane == 0) red[w] = loc;
    __syncthreads();
    float tr = red[0] + red[1] + red[2] + red[3] +
               red[4] + red[5] + red[6] + red[7];

    float s     = sv[0];
    float inv   = s / tr;
    float onems = 1.f - s;
    float* outr = out + (size_t)b * 16384;
    float* outi = out + 8388608 + (size_t)b * 16384;

    #define EPI(SRV, SIV, MT, NT) do {                                          \
        int colc = kh * 64 + wn * 32 + (NT) * 16 + c16;                         \
        _Pragma("unroll")                                                       \
        for (int r = 0; r < 4; ++r) {                                           \
            int row = wm * 32 + (MT) * 16 + g4 * 4 + r;                         \
            float vr = SRV[r] * inv;                                            \
            if (row == colc) vr += onems * pv[row];                             \
            outr[row * 128 + colc] = vr;                                        \
            outi[row * 128 + colc] = SIV[r] * inv;                              \
        }                                                                       \
    } while (0)

    EPI(sR00, sI00, 0, 0);
    EPI(sR01, sI01, 0, 1);
    EPI(sR10, sI10, 1, 0);
    EPI(sR11, sI11, 1, 1);
    #undef EPI
}

extern "C" void kernel_launch(void* const* d_in, const int* in_sizes, int n_in,
                              void* d_out, int out_size, void* d_ws, size_t ws_size,
                              hipStream_t stream) {
    (void)in_sizes; (void)n_in; (void)out_size; (void)ws_size;
    const float* xr = (const float*)d_in[0];
    const float* xi = (const float*)d_in[1];
    const float* wt = (const float*)d_in[2];
    const float* rw = (const float*)d_in[3];
    const float* lm = (const float*)d_in[4];

    short* Ur  = (short*)d_ws;                        // 64 KB row-major bf16
    short* Ui  = (short*)((char*)d_ws + 65536);       // 64 KB
    short* Upr = (short*)((char*)d_ws + 131072);      // 64 KB packed frags
    short* Upi = (short*)((char*)d_ws + 196608);      // 64 KB
    short* Qrb = (short*)((char*)d_ws + 262144);      // 128 KB row-major bf16
    short* Qib = (short*)((char*)d_ws + 393216);      // 128 KB
    float* pv  = (float*)((char*)d_ws + 524288);      // 128 f32
    float* sv  = pv + 128;                            // 1 f32
    float* o   = (float*)d_out;

    qprep_u<<<dim3(128), dim3(256), 0, stream>>>(wt, Ur, Ui, Upr, Upi);
    qprep_ps<<<dim3(1), dim3(64), 0, stream>>>(rw, lm, pv, sv);
    qprep_q<<<dim3(256), dim3(256), 0, stream>>>(wt, Qrb, Qib);
    qfused<<<dim3(1024), dim3(512), 0, stream>>>(xr, xi, Ur, Ui, Upr, Upi,
                                                 Qrb, Qib, pv, sv, o);
}

// Round 17
// 149.165 us; speedup vs baseline: 2.0280x; 1.0575x over previous
//
#include <hip/hip_runtime.h>
#include <hip/hip_bf16.h>

// QDense: out = s * (U X U^H)[:128,:128] / tr + (1-s) * diag(softmax(rand_w))
// B=512, D=256, O=128.
// Round-17 = round-16 (157us best) with held-prefetch footprint halved:
//   single 16-reg held buffer H, slice-granular stagger:
//     pair Q: write H(=sliceA pair Q+1)+TRDOT; H <- sliceB pair Q+1;
//             CONS(0..3); write H(sliceB)+TRDOT; H <- sliceA pair Q+2;
//             CONS(4..7); Yt; barrier.
//   -> 16 fewer arch VGPRs at peak; goal: kill the ~52MB/dispatch scratch
//   spill (r16 WRITE 118.8MB vs 67 ideal).
// Everything else r16: full-row 1KB coalesced X loads, f32->bf16 at staging,
// 2 pair-slot X ring, XCD sibling pairing, U-half swizzled LDS, packed-U
// stage B, TRDOT trace on staging regs, 1 barrier/pair + lgkmcnt only.
// LDS: U 64K + Yt 16K + X-ring 64K = 144KB -> 1 block/CU.  1024 blocks, 512 thr.

typedef __attribute__((ext_vector_type(4))) float f32x4;
typedef __attribute__((ext_vector_type(8))) short bf16x8;

static __device__ __forceinline__ short f2bf(float f) {   // prep kernels only
    unsigned u = __float_as_uint(f);
    u += 0x7fffu + ((u >> 16) & 1u);
    return (short)(u >> 16);
}

static __device__ __forceinline__ float b2f(unsigned short h) {
    return __uint_as_float(((unsigned)h) << 16);
}

static __device__ __forceinline__ unsigned cvtpk2(float lo, float hi) {
    union { __hip_bfloat162 h; unsigned u; } c;
    c.h = __float22bfloat162_rn(float2{lo, hi});
    return c.u;
}

static __device__ __forceinline__ uint2 cvt2(f32x4 v) {
    uint2 r;
    r.x = cvtpk2(v[0], v[1]);
    r.y = cvtpk2(v[2], v[3]);
    return r;
}

static __device__ __forceinline__ f32x4 mfma16(bf16x8 a, bf16x8 b, f32x4 c) {
    return __builtin_amdgcn_mfma_f32_16x16x32_bf16(a, b, c, 0, 0, 0);
}

// ---- prep: U -> bf16 row-major (Ur/Ui) and fragment-packed (Upr/Upi) ----
__global__ void qprep_u(const float* __restrict__ wt,
                        short* __restrict__ Ur,  short* __restrict__ Ui,
                        short* __restrict__ Upr, short* __restrict__ Upi) {
    int idx = blockIdx.x * 256 + threadIdx.x;     // j*256+k, j<128
    int j = idx >> 8, k = idx & 255;
    float2 v = ((const float2*)wt)[idx];
    short br = f2bf(v.x), bi = f2bf(v.y);
    Ur[idx] = br;
    Ui[idx] = bi;
    int g = j >> 4, s = k >> 5;
    int lanep = (j & 15) | (((k >> 3) & 3) << 4);
    int p = ((g * 8 + s) * 64 + lanep) * 8 + (k & 7);
    Upr[p] = br;
    Upi[p] = bi;
}

__global__ void qprep_ps(const float* __restrict__ rw, const float* __restrict__ lm,
                         float* __restrict__ pv, float* __restrict__ sv) {
    int t = threadIdx.x;
    float w0 = rw[t], w1 = rw[t + 64];
    float m = fmaxf(w0, w1);
    #pragma unroll
    for (int o = 32; o > 0; o >>= 1) m = fmaxf(m, __shfl_xor(m, o));
    float e0 = expf(w0 - m), e1 = expf(w1 - m);
    float ss = e0 + e1;
    #pragma unroll
    for (int o = 32; o > 0; o >>= 1) ss += __shfl_xor(ss, o);
    pv[t] = e0 / ss;
    pv[t + 64] = e1 / ss;
    if (t == 0) sv[0] = 1.f / (1.f + expf(-lm[0]));
}

// Q[j][k] = P[k][j], P = U_sub^H U_sub  (bf16, row-major)
__global__ void qprep_q(const float* __restrict__ wt,
                        short* __restrict__ Qrb, short* __restrict__ Qib) {
    int j = blockIdx.x;
    int k = threadIdx.x;
    float ar = 0.f, ai = 0.f;
    for (int i = 0; i < 128; ++i) {
        float2 uk = ((const float2*)wt)[i * 256 + k];
        float2 uj = ((const float2*)wt)[i * 256 + j];
        ar += uk.x * uj.x + uk.y * uj.y;
        ai += uk.x * uj.y - uk.y * uj.x;
    }
    Qrb[j * 256 + k] = f2bf(ar);
    Qib[j * 256 + k] = f2bf(ai);
}

#define PB(Q) ((Q) * 32)                 // pair row base (rows in batch)

// ---- elementwise trace dot on held regs (rows RB+sr0, RB+sr1) ----
#define TRDOT(RB, A0, A1, A2, A3) do {                                          \
    const int qo0 = ((RB) + sr0) * 256 + xl4;                                   \
    const int qo1 = ((RB) + sr1) * 256 + xl4;                                   \
    ushort4 hr0 = *(const ushort4*)(Qrb + qo0);                                 \
    ushort4 hr1 = *(const ushort4*)(Qrb + qo1);                                 \
    ushort4 hi0 = *(const ushort4*)(Qib + qo0);                                 \
    ushort4 hi1 = *(const ushort4*)(Qib + qo1);                                 \
    tracc += A0[0]*b2f(hr0.x) + A0[1]*b2f(hr0.y)                                \
           + A0[2]*b2f(hr0.z) + A0[3]*b2f(hr0.w);                               \
    tracc += A1[0]*b2f(hr1.x) + A1[1]*b2f(hr1.y)                                \
           + A1[2]*b2f(hr1.z) + A1[3]*b2f(hr1.w);                               \
    tracc -= A2[0]*b2f(hi0.x) + A2[1]*b2f(hi0.y)                                \
           + A2[2]*b2f(hi0.z) + A2[3]*b2f(hi0.w);                               \
    tracc -= A3[0]*b2f(hi1.x) + A3[1]*b2f(hi1.y)                                \
           + A3[2]*b2f(hi1.z) + A3[3]*b2f(hi1.w);                               \
} while (0)

// ---- consume one ks step ----
#define CONS(KS) do {                                                           \
    const int ko = (KS) * 64 + g16;                                             \
    bf16x8 axr = *(const bf16x8*)(xsp + aro + (ko ^ aswz));                     \
    bf16x8 axi = *(const bf16x8*)(xsp + 8192 + aro + (ko ^ aswz));              \
    bf16x8 bur = *(const bf16x8*)(smem + uob + (ko ^ uswz));                    \
    bf16x8 bui = *(const bf16x8*)(smem + 32768 + uob + (ko ^ uswz));            \
    bf16x8 axrn = axr ^ (short)0x8000;                                          \
    yR = mfma16(axr,  bur, yR);                                                 \
    yR = mfma16(axi,  bui, yR);                                                 \
    yI = mfma16(axi,  bur, yI);                                                 \
    yI = mfma16(axrn, bui, yI);                                                 \
} while (0)

// ---- one phase-pair (Q literal 0..7), slice-granular held buffer H ----
#define PAIR(Q) do {                                                            \
    const char* xsp = smem + 81920 + ((Q) & 1) * 32768 + wj16k;                 \
    if ((Q) < 7) {   /* write H = slice A of pair Q+1 (issued mid pair Q-1) */  \
        char* wp0 = smem + 81920 + (((Q) + 1) & 1) * 32768;                     \
        *(uint2*)(wp0 + wr0o)        = cvt2(hA0);                               \
        *(uint2*)(wp0 + wr1o)        = cvt2(hA1);                               \
        *(uint2*)(wp0 + 8192 + wr0o) = cvt2(hA2);                               \
        *(uint2*)(wp0 + 8192 + wr1o) = cvt2(hA3);                               \
        TRDOT(PB((Q) + 1), hA0, hA1, hA2, hA3);                                 \
        const int r0 = (PB((Q) + 1) + 16 + sr0) * 256 + xl4;                    \
        const int r1 = (PB((Q) + 1) + 16 + sr1) * 256 + xl4;                    \
        hA0 = *(const f32x4*)(xr + xgb + r0);   /* H <- slice B of pair Q+1 */  \
        hA1 = *(const f32x4*)(xr + xgb + r1);                                   \
        hA2 = *(const f32x4*)(xi + xgb + r0);                                   \
        hA3 = *(const f32x4*)(xi + xgb + r1);                                   \
    }                                                                           \
    __builtin_amdgcn_sched_barrier(0);                                          \
    CONS(0); CONS(1); CONS(2); CONS(3);                                         \
    if ((Q) < 7) {   /* write H = slice B of pair Q+1 */                        \
        char* wp1 = smem + 81920 + (((Q) + 1) & 1) * 32768 + 16384;             \
        *(uint2*)(wp1 + wr0o)        = cvt2(hA0);                               \
        *(uint2*)(wp1 + wr1o)        = cvt2(hA1);                               \
        *(uint2*)(wp1 + 8192 + wr0o) = cvt2(hA2);                               \
        *(uint2*)(wp1 + 8192 + wr1o) = cvt2(hA3);                               \
        TRDOT(PB((Q) + 1) + 16, hA0, hA1, hA2, hA3);                            \
    }                                                                           \
    if ((Q) < 6) {   /* H <- slice A of pair Q+2 */                             \
        const int r0 = (PB((Q) + 2) + sr0) * 256 + xl4;                         \
        const int r1 = (PB((Q) + 2) + sr1) * 256 + xl4;                         \
        hA0 = *(const f32x4*)(xr + xgb + r0);                                   \
        hA1 = *(const f32x4*)(xr + xgb + r1);                                   \
        hA2 = *(const f32x4*)(xi + xgb + r0);                                   \
        hA3 = *(const f32x4*)(xi + xgb + r1);                                   \
    }                                                                           \
    __builtin_amdgcn_sched_barrier(0);                                          \
    CONS(4); CONS(5); CONS(6); CONS(7);                                         \
    {                                                                           \
        const int yw = ((Q) & 1) ? ytw1 : ytw0;                                 \
        *(uint2*)(smem + 65536 + yw) = cvt2(yR);                                \
        *(uint2*)(smem + 73728 + yw) = cvt2(yI);                                \
    }                                                                           \
    yR = zero; yI = zero;                                                       \
    asm volatile("s_waitcnt lgkmcnt(0)" ::: "memory");                          \
    __builtin_amdgcn_sched_barrier(0);                                          \
    __builtin_amdgcn_s_barrier();                                               \
    __builtin_amdgcn_sched_barrier(0);                                          \
} while (0)

// ---- stage B (packed-U A-operand) ----
#define STAGEB_KS(JT, KS2) do {                                                 \
    const int s2 = (JT) * 2 + (KS2);                                            \
    bf16x8 aur0 = *(const bf16x8*)(Upr + ((wm * 2 + 0) * 8 + s2) * 512 + l8);   \
    bf16x8 aui0 = *(const bf16x8*)(Upi + ((wm * 2 + 0) * 8 + s2) * 512 + l8);   \
    bf16x8 aur1 = *(const bf16x8*)(Upr + ((wm * 2 + 1) * 8 + s2) * 512 + l8);   \
    bf16x8 aui1 = *(const bf16x8*)(Upi + ((wm * 2 + 1) * 8 + s2) * 512 + l8);   \
    bf16x8 auin0 = aui0 ^ (short)0x8000;                                        \
    bf16x8 auin1 = aui1 ^ (short)0x8000;                                        \
    {                                                                           \
        const int off = ybA + (((KS2) * 64 + g16) ^ ysA);                       \
        bf16x8 byr = *(const bf16x8*)(smem + 65536 + off);                      \
        bf16x8 byi = *(const bf16x8*)(smem + 73728 + off);                      \
        sR00 = mfma16(aur0,  byr, sR00); sR00 = mfma16(auin0, byi, sR00);       \
        sI00 = mfma16(aui0,  byr, sI00); sI00 = mfma16(aur0,  byi, sI00);       \
        sR10 = mfma16(aur1,  byr, sR10); sR10 = mfma16(auin1, byi, sR10);       \
        sI10 = mfma16(aui1,  byr, sI10); sI10 = mfma16(aur1,  byi, sI10);       \
    }                                                                           \
    {                                                                           \
        const int off = ybB + (((KS2) * 64 + g16) ^ ysB);                       \
        bf16x8 byr = *(const bf16x8*)(smem + 65536 + off);                      \
        bf16x8 byi = *(const bf16x8*)(smem + 73728 + off);                      \
        sR01 = mfma16(aur0,  byr, sR01); sR01 = mfma16(auin0, byi, sR01);       \
        sI01 = mfma16(aui0,  byr, sI01); sI01 = mfma16(aur0,  byi, sI01);       \
        sR11 = mfma16(aur1,  byr, sR11); sR11 = mfma16(auin1, byi, sR11);       \
        sI11 = mfma16(aui1,  byr, sI11); sI11 = mfma16(aur1,  byi, sI11);       \
    }                                                                           \
} while (0)

#define STAGEB_PASS(JT) do {                                                    \
    STAGEB_KS(JT, 0);                                                           \
    STAGEB_KS(JT, 1);                                                           \
    asm volatile("s_waitcnt lgkmcnt(0)" ::: "memory");                          \
    __builtin_amdgcn_sched_barrier(0);                                          \
    __builtin_amdgcn_s_barrier();      /* Yt reads done before next writes */   \
    __builtin_amdgcn_sched_barrier(0);                                          \
} while (0)

// ---- main fused kernel ----
__global__ __launch_bounds__(512, 1) void qfused(
    const float* __restrict__ xr, const float* __restrict__ xi,
    const short* __restrict__ Urg, const short* __restrict__ Uig,
    const short* __restrict__ Upr, const short* __restrict__ Upi,
    const short* __restrict__ Qrb, const short* __restrict__ Qib,
    const float* __restrict__ pv, const float* __restrict__ sv,
    float* __restrict__ out)
{
    // [0,65536) U-half swizzled (R 0, I 32768); [65536,81920) Yt (R/I);
    // [81920,147456) X ring: 2 pair-slots x (sliceA 16KB + sliceB 16KB).
    __shared__ __align__(16) char smem[147456];

    const int bx   = blockIdx.x;
    // XCD sibling pairing: batch b's two kh-blocks share bx%8 (same XCD).
    const int b    = ((bx >> 4) << 3) | (bx & 7);
    const int kh   = (bx >> 3) & 1;
    const int tid  = threadIdx.x;
    const int lane = tid & 63;
    const int w    = tid >> 6;
    const int c16  = lane & 15;
    const int g4   = lane >> 4;
    const int g8   = g4 * 8;
    const int g16  = g4 * 16;
    const int l8   = lane * 8;

    const int wj    = w >> 2;            // my slice within pair (0/1)
    const int wk    = w & 3;             // my k'-group
    const int wj16k = wj * 16384;
    const int wm    = w >> 1;            // stage-B row-quarter
    const int wn    = w & 1;             // stage-B k'-half-of-half

    // X staging: wave stages slot-rows {w*2, w*2+1}; lane covers bytes l*16.
    const int sr0 = w * 2, sr1 = w * 2 + 1;
    const int xl4 = lane * 4;            // float offset within row
    const int xgb = b << 16;
    const int wr0o = sr0 * 512 + ((((lane >> 1) << 4) ^ ((sr0 & 7) << 4))) + ((lane & 1) << 3);
    const int wr1o = sr1 * 512 + ((((lane >> 1) << 4) ^ ((sr1 & 7) << 4))) + ((lane & 1) << 3);

    // consume: A from X-slot row c16; B from U-LDS row wk*16+c16
    const int aro  = c16 * 512;
    const int aswz = (c16 & 7) << 4;
    const int ukl  = wk * 16 + c16;
    const int uob  = ukl * 512;
    const int uswz = (ukl & 7) << 4;

    // Yt write offsets (pair 0 / pair 1 within a pass)
    const int ytr  = ukl;
    const int ytk  = (ytr & 7) << 4;
    const int ytw0 = ytr * 128 + ((wj * 32 + g8) ^ ytk);
    const int ytw1 = ytr * 128 + ((64 + wj * 32 + g8) ^ ytk);

    // stage-B Yt read offsets
    const int ybA = (wn * 32 + c16) * 128;
    const int ybB = (wn * 32 + 16 + c16) * 128;
    const int ysA = ((wn * 32 + c16) & 7) << 4;
    const int ysB = ((wn * 32 + 16 + c16) & 7) << 4;

    // ---- stage U-half into swizzled LDS (r3-proven) ----
    #pragma unroll
    for (int q = 0; q < 4; ++q) {
        int c    = tid + q * 512;
        int row  = c >> 5;
        int slot = c & 31;
        int ss   = slot ^ (row & 7);
        const short* sr = Urg + (size_t)(kh * 64 + row) * 256 + ss * 8;
        const short* si = Uig + (size_t)(kh * 64 + row) * 256 + ss * 8;
        *(bf16x8*)(smem + row * 512 + slot * 16)         = *(const bf16x8*)sr;
        *(bf16x8*)(smem + 32768 + row * 512 + slot * 16) = *(const bf16x8*)si;
    }

    f32x4 zero = {0.f, 0.f, 0.f, 0.f};
    f32x4 sR00 = zero, sR01 = zero, sR10 = zero, sR11 = zero;
    f32x4 sI00 = zero, sI01 = zero, sI10 = zero, sI11 = zero;
    float tracc = 0.f;
    f32x4 yR = zero, yI = zero;
    f32x4 hA0, hA1, hA2, hA3;            // single 16-reg held slice buffer

    // ---- prologue: direct-stage pair 0 (+TRDOT); H <- pair-1 slice A ----
    {
        const int r0 = (PB(0) + sr0) * 256 + xl4;
        const int r1 = (PB(0) + sr1) * 256 + xl4;
        const int r2 = (PB(0) + 16 + sr0) * 256 + xl4;
        const int r3 = (PB(0) + 16 + sr1) * 256 + xl4;
        f32x4 a0 = *(const f32x4*)(xr + xgb + r0);
        f32x4 a1 = *(const f32x4*)(xr + xgb + r1);
        f32x4 a2 = *(const f32x4*)(xi + xgb + r0);
        f32x4 a3 = *(const f32x4*)(xi + xgb + r1);
        f32x4 b0 = *(const f32x4*)(xr + xgb + r2);
        f32x4 b1 = *(const f32x4*)(xr + xgb + r3);
        f32x4 b2 = *(const f32x4*)(xi + xgb + r2);
        f32x4 b3 = *(const f32x4*)(xi + xgb + r3);
        const int r4 = (PB(1) + sr0) * 256 + xl4;
        const int r5 = (PB(1) + sr1) * 256 + xl4;
        hA0 = *(const f32x4*)(xr + xgb + r4);
        hA1 = *(const f32x4*)(xr + xgb + r5);
        hA2 = *(const f32x4*)(xi + xgb + r4);
        hA3 = *(const f32x4*)(xi + xgb + r5);
        char* w0p = smem + 81920;
        char* w1p = smem + 81920 + 16384;
        *(uint2*)(w0p + wr0o)        = cvt2(a0);
        *(uint2*)(w0p + wr1o)        = cvt2(a1);
        *(uint2*)(w0p + 8192 + wr0o) = cvt2(a2);
        *(uint2*)(w0p + 8192 + wr1o) = cvt2(a3);
        *(uint2*)(w1p + wr0o)        = cvt2(b0);
        *(uint2*)(w1p + wr1o)        = cvt2(b1);
        *(uint2*)(w1p + 8192 + wr0o) = cvt2(b2);
        *(uint2*)(w1p + 8192 + wr1o) = cvt2(b3);
        TRDOT(PB(0),      a0, a1, a2, a3);
        TRDOT(PB(0) + 16, b0, b1, b2, b3);
    }
    asm volatile("s_waitcnt lgkmcnt(0)" ::: "memory");
    __builtin_amdgcn_sched_barrier(0);
    __builtin_amdgcn_s_barrier();
    __builtin_amdgcn_sched_barrier(0);

    PAIR(0);
    PAIR(1);
    STAGEB_PASS(0);
    PAIR(2);
    PAIR(3);
    STAGEB_PASS(1);
    PAIR(4);
    PAIR(5);
    STAGEB_PASS(2);
    PAIR(6);
    PAIR(7);
    STAGEB_KS(3, 0);
    STAGEB_KS(3, 1);

    // ---- trace: elementwise dot summed over all lanes/waves ----
    float loc = tracc;
    #pragma unroll
    for (int o = 32; o > 0; o >>= 1) loc += __shfl_xor(loc, o);
    __syncthreads();                      // Yt dead; reuse for reduction
    float* red = (float*)(smem + 65536);
    if (lane == 0) red[w] = loc;
    __syncthreads();
    float tr = red[0] + red[1] + red[2] + red[3] +
               red[4] + red[5] + red[6] + red[7];

    float s     = sv[0];
    float inv   = s / tr;
    float onems = 1.f - s;
    float* outr = out + (size_t)b * 16384;
    float* outi = out + 8388608 + (size_t)b * 16384;

    #define EPI(SRV, SIV, MT, NT) do {                                          \
        int colc = kh * 64 + wn * 32 + (NT) * 16 + c16;                         \
        _Pragma("unroll")                                                       \
        for (int r = 0; r < 4; ++r) {                                           \
            int row = wm * 32 + (MT) * 16 + g4 * 4 + r;                         \
            float vr = SRV[r] * inv;                                            \
            if (row == colc) vr += onems * pv[row];                             \
            outr[row * 128 + colc] = vr;                                        \
            outi[row * 128 + colc] = SIV[r] * inv;                              \
        }                                                                       \
    } while (0)

    EPI(sR00, sI00, 0, 0);
    EPI(sR01, sI01, 0, 1);
    EPI(sR10, sI10, 1, 0);
    EPI(sR11, sI11, 1, 1);
    #undef EPI
}

extern "C" void kernel_launch(void* const* d_in, const int* in_sizes, int n_in,
                              void* d_out, int out_size, void* d_ws, size_t ws_size,
                              hipStream_t stream) {
    (void)in_sizes; (void)n_in; (void)out_size; (void)ws_size;
    const float* xr = (const float*)d_in[0];
    const float* xi = (const float*)d_in[1];
    const float* wt = (const float*)d_in[2];
    const float* rw = (const float*)d_in[3];
    const float* lm = (const float*)d_in[4];

    short* Ur  = (short*)d_ws;                        // 64 KB row-major bf16
    short* Ui  = (short*)((char*)d_ws + 65536);       // 64 KB
    short* Upr = (short*)((char*)d_ws + 131072);      // 64 KB packed frags
    short* Upi = (short*)((char*)d_ws + 196608);      // 64 KB
    short* Qrb = (short*)((char*)d_ws + 262144);      // 128 KB row-major bf16
    short* Qib = (short*)((char*)d_ws + 393216);      // 128 KB
    float* pv  = (float*)((char*)d_ws + 524288);      // 128 f32
    float* sv  = pv + 128;                            // 1 f32
    float* o   = (float*)d_out;

    qprep_u<<<dim3(128), dim3(256), 0, stream>>>(wt, Ur, Ui, Upr, Upi);
    qprep_ps<<<dim3(1), dim3(64), 0, stream>>>(rw, lm, pv, sv);
    qprep_q<<<dim3(256), dim3(256), 0, stream>>>(wt, Qrb, Qib);
    qfused<<<dim3(1024), dim3(512), 0, stream>>>(xr, xi, Ur, Ui, Upr, Upi,
                                                 Qrb, Qib, pv, sv, o);
}